// Round 1
// 1047.501 us; speedup vs baseline: 1.1855x; 1.1855x over previous
//
#include <hip/hip_runtime.h>
#include <math.h>
#include <stdint.h>

// Problem constants
static const int VOC  = 32000;
static const int VT_  = 32100;

typedef __attribute__((ext_vector_type(8))) short bf16x8_t;
typedef __attribute__((ext_vector_type(4))) float f32x4_t;

__device__ __forceinline__ unsigned short f2bf(float f) {
  union { float f; unsigned int u; } v; v.f = f;
  unsigned int u = v.u;
  u = u + 0x7FFFu + ((u >> 16) & 1u);   // RNE
  return (unsigned short)(u >> 16);
}

// ---------------------------------------------------------------- utilities
__global__ void k_conv(const float* __restrict__ src, unsigned short* __restrict__ dst, int n4) {
  int i = blockIdx.x * blockDim.x + threadIdx.x;
  int stride = gridDim.x * blockDim.x;
  for (; i < n4; i += stride) {
    float4 f = ((const float4*)src)[i];
    ushort4 o;
    o.x = f2bf(f.x); o.y = f2bf(f.y); o.z = f2bf(f.z); o.w = f2bf(f.w);
    ((ushort4*)dst)[i] = o;
  }
}

// enc_scores = tanh(encoded @ Wo^T + Wo_b): M=4096 (b,s), N=256, K=512
__global__ __launch_bounds__(256) void k_enc(const float* __restrict__ enc,
                                             const float* __restrict__ wo,
                                             const float* __restrict__ wob,
                                             float* __restrict__ outp) {
  int bm = blockIdx.x, bn = blockIdx.y;
  int tid = threadIdx.x;
  int ti = tid & 15, tj = tid >> 4;
  int r0 = bm * 64 + ti * 4;
  int n0 = bn * 64 + tj * 4;
  const float4* A[4]; const float4* B[4];
#pragma unroll
  for (int i = 0; i < 4; i++) A[i] = (const float4*)(enc + (size_t)(r0 + i) * 512);
#pragma unroll
  for (int j = 0; j < 4; j++) B[j] = (const float4*)(wo + (size_t)(n0 + j) * 512);
  float acc[4][4];
#pragma unroll
  for (int i = 0; i < 4; i++)
#pragma unroll
    for (int j = 0; j < 4; j++) acc[i][j] = 0.f;
  for (int k = 0; k < 128; k++) {
    float4 a[4], b[4];
#pragma unroll
    for (int i = 0; i < 4; i++) a[i] = A[i][k];
#pragma unroll
    for (int j = 0; j < 4; j++) b[j] = B[j][k];
#pragma unroll
    for (int i = 0; i < 4; i++)
#pragma unroll
      for (int j = 0; j < 4; j++)
        acc[i][j] += a[i].x * b[j].x + a[i].y * b[j].y + a[i].z * b[j].z + a[i].w * b[j].w;
  }
#pragma unroll
  for (int i = 0; i < 4; i++)
#pragma unroll
    for (int j = 0; j < 4; j++)
      outp[(size_t)(r0 + i) * 256 + n0 + j] = tanhf(acc[i][j] + wob[n0 + j]);
}

// Xg = embed[inputs] @ Wih[:, :256]^T + b_ih: M=2048, N=768, K=256
__global__ __launch_bounds__(256) void k_xg(const float* __restrict__ embed,
                                            const int* __restrict__ inputs,
                                            const float* __restrict__ wih,
                                            const float* __restrict__ bih,
                                            float* __restrict__ xg) {
  int bm = blockIdx.x, bn = blockIdx.y;
  int tid = threadIdx.x;
  int ti = tid & 15, tj = tid >> 4;
  int r0 = bm * 64 + ti * 4;
  int n0 = bn * 64 + tj * 4;
  const float4* A[4]; const float4* B[4];
#pragma unroll
  for (int i = 0; i < 4; i++) A[i] = (const float4*)(embed + (size_t)inputs[r0 + i] * 256);
#pragma unroll
  for (int j = 0; j < 4; j++) B[j] = (const float4*)(wih + (size_t)(n0 + j) * 768);
  float acc[4][4];
#pragma unroll
  for (int i = 0; i < 4; i++)
#pragma unroll
    for (int j = 0; j < 4; j++) acc[i][j] = 0.f;
  for (int k = 0; k < 64; k++) {
    float4 a[4], b[4];
#pragma unroll
    for (int i = 0; i < 4; i++) a[i] = A[i][k];
#pragma unroll
    for (int j = 0; j < 4; j++) b[j] = B[j][k];
#pragma unroll
    for (int i = 0; i < 4; i++)
#pragma unroll
      for (int j = 0; j < 4; j++)
        acc[i][j] += a[i].x * b[j].x + a[i].y * b[j].y + a[i].z * b[j].z + a[i].w * b[j].w;
  }
#pragma unroll
  for (int i = 0; i < 4; i++)
#pragma unroll
    for (int j = 0; j < 4; j++)
      xg[(size_t)(r0 + i) * 768 + n0 + j] = acc[i][j] + bih[n0 + j];
}

// s0 = encoded[:, -1, :] @ bridge^T
__global__ __launch_bounds__(256) void k_s0(const float* __restrict__ enc,
                                            const float* __restrict__ bw,
                                            float* __restrict__ s0) {
  int b = blockIdx.x, h = threadIdx.x;
  const float4* a4 = (const float4*)(enc + ((size_t)b * 128 + 127) * 512);
  const float4* w4 = (const float4*)(bw + (size_t)h * 512);
  float acc = 0.f;
  for (int k = 0; k < 128; k++) {
    float4 a = a4[k], w = w4[k];
    acc += a.x * w.x + a.y * w.y + a.z * w.z + a.w * w.w;
  }
  s0[b * 256 + h] = acc;
}

// ENC_ih[b,s,:] = encoded[b,s,:] @ Wih[:, 256:768]^T  -- only where token ever matches
__global__ __launch_bounds__(256) void k_encih(const float* __restrict__ enc,
                                               const float* __restrict__ wih,
                                               const int* __restrict__ encidx,
                                               const int* __restrict__ inputs,
                                               float* __restrict__ encih) {
  __shared__ int flag;
  int bs = blockIdx.x;
  int b = bs >> 7;
  int tid = threadIdx.x;
  int idx = encidx[bs];
  if (tid < 64) {
    unsigned long long m = __ballot(inputs[b * 64 + tid] == idx);
    if (tid == 0) flag = (m != 0ULL);
  }
  __syncthreads();
  if (!flag) return;
  const float4* e4 = (const float4*)(enc + (size_t)bs * 512);
  for (int d = tid; d < 768; d += 256) {
    const float4* w4 = (const float4*)(wih + (size_t)d * 768 + 256);
    float acc = 0.f;
    for (int k = 0; k < 128; k++) {
      float4 e = e4[k], w = w4[k];
      acc += e.x * w.x + e.y * w.y + e.z * w.z + e.w * w.w;
    }
    encih[(size_t)bs * 768 + d] = acc;
  }
}

// -------------------------------------------------------- sequential GRU
// One block per batch row b: 768 threads = 12 waves.
// W_hh stored bf16 row-major [768][256]; each wave owns 64 output columns
// (full K) and computes them with mfma_f32_16x16x32_bf16, with the s-row
// broadcast across all 16 A-rows (A-frag depends only on lane>>4, so every
// C row equals s @ W^T). Halves the per-step L2->L1 weight stream (786->393
// KB) which was the measured per-step floor, and moves the MACs off the VALU.
// All per-step state is block-local: NO cross-workgroup communication.
__global__ __launch_bounds__(768, 1) void k_seq(
    const unsigned short* __restrict__ whb,  // [768][256] bf16 W_hh
    const float* __restrict__ bhh,
    const float* __restrict__ xg, const float* __restrict__ encsc,
    const float* __restrict__ encih, const int* __restrict__ encidx,
    const int* __restrict__ inputs, const float* __restrict__ s0,
    float* __restrict__ S32, unsigned short* __restrict__ S16) {
  __shared__ float sbuf[256];
  __shared__ __align__(16) unsigned short sb16[256];
  __shared__ float ghp[768];
  __shared__ float psis[128];
  __shared__ int mlist[128];
  __shared__ int eidx_sh[128];
  __shared__ int inp_sh[64];
  __shared__ int mcnt_sh;
  int b = blockIdx.x;
  int tid = threadIdx.x;
  int wid = tid >> 6, lane = tid & 63;
  int quad = lane >> 4, l15 = lane & 15;
  int n0 = wid * 64;                 // this wave's 64 output columns
  int h = tid;                       // gate thread id (tid<256)
  float bR = 0.f, bZ = 0.f, bN = 0.f, ctxR = 0.f, ctxZ = 0.f, ctxN = 0.f;
  if (tid < 256) {
    bR = bhh[h]; bZ = bhh[256 + h]; bN = bhh[512 + h];
    float v = s0[b * 256 + tid];
    sbuf[tid] = v;
    sb16[tid] = f2bf(v);
  }
  if (tid < 128) eidx_sh[tid] = encidx[b * 128 + tid];
  if (tid < 64) inp_sh[tid] = inputs[b * 64 + tid];
  __syncthreads();
  // B-frag row pointers: W row (n0 + nt*16 + l15), k-offset quad*8. Fixed
  // across steps; kt advances by 32 bf16 (64 B) -> immediate offsets.
  const unsigned short* wp0 = whb + (size_t)(n0 +  0 + l15) * 256 + quad * 8;
  const unsigned short* wp1 = whb + (size_t)(n0 + 16 + l15) * 256 + quad * 8;
  const unsigned short* wp2 = whb + (size_t)(n0 + 32 + l15) * 256 + quad * 8;
  const unsigned short* wp3 = whb + (size_t)(n0 + 48 + l15) * 256 + quad * 8;
  for (int t = 0; t < 64; t++) {
    int r = b * 64 + t;
    // --- gh = s @ W_hh^T via MFMA (full K per wave, 64 cols)
    f32x4_t a0 = {0.f,0.f,0.f,0.f}, a1 = {0.f,0.f,0.f,0.f};
    f32x4_t a2 = {0.f,0.f,0.f,0.f}, a3 = {0.f,0.f,0.f,0.f};
#pragma unroll
    for (int kt = 0; kt < 8; kt++) {
      bf16x8_t af = *(const bf16x8_t*)(sb16 + kt * 32 + quad * 8);
      bf16x8_t b0 = *(const bf16x8_t*)(wp0 + kt * 32);
      bf16x8_t b1 = *(const bf16x8_t*)(wp1 + kt * 32);
      bf16x8_t b2 = *(const bf16x8_t*)(wp2 + kt * 32);
      bf16x8_t b3 = *(const bf16x8_t*)(wp3 + kt * 32);
      a0 = __builtin_amdgcn_mfma_f32_16x16x32_bf16(af, b0, a0, 0, 0, 0);
      a1 = __builtin_amdgcn_mfma_f32_16x16x32_bf16(af, b1, a1, 0, 0, 0);
      a2 = __builtin_amdgcn_mfma_f32_16x16x32_bf16(af, b2, a2, 0, 0, 0);
      a3 = __builtin_amdgcn_mfma_f32_16x16x32_bf16(af, b3, a3, 0, 0, 0);
    }
    // C rows are identical (A replicated); row0 lives in lanes 0-15, reg 0.
    if (lane < 16) {
      ghp[n0 +      lane] = a0[0];
      ghp[n0 + 16 + lane] = a1[0];
      ghp[n0 + 32 + lane] = a2[0];
      ghp[n0 + 48 + lane] = a3[0];
    }
    __syncthreads();                                   // B1: gh complete
    if (tid < 256) {
      float hr = ghp[h] + bR;
      float hz = ghp[256 + h] + bZ;
      float hn = ghp[512 + h] + bN;
      const float* xr = xg + (size_t)r * 768;
      float gr = xr[h] + ctxR;
      float gz = xr[256 + h] + ctxZ;
      float gn = xr[512 + h] + ctxN;
      float rgate = 1.f / (1.f + expf(-(gr + hr)));
      float zgate = 1.f / (1.f + expf(-(gz + hz)));
      float ngate = tanhf(gn + rgate * hn);
      float sold = sbuf[h];
      float snew = (1.f - zgate) * ngate + zgate * sold;
      S32[(size_t)r * 256 + h] = snew;
      S16[(size_t)r * 256 + h] = f2bf(snew);
      sbuf[h] = snew;                                  // own-element RMW, safe
      sb16[h] = f2bf(snew);
    }
    if (tid == 256) mcnt_sh = 0;
    __syncthreads();                                   // B2: s_t complete
    if (t == 63) break;
    // --- matched-position copy-attention for ctx(t) -> used at step t+1
    int inp_t = inp_sh[t];
    if (tid < 128 && eidx_sh[tid] == inp_t) {
      int p = atomicAdd(&mcnt_sh, 1);
      mlist[p] = tid;
    }
    __syncthreads();                                   // B3
    int mc = mcnt_sh;
    if (mc > 0) {
      int wv = tid >> 6, ln = tid & 63;
      for (int j = wv; j < mc; j += 12) {
        int s = mlist[j];
        const float4* e4 = (const float4*)(encsc + (size_t)(b * 128 + s) * 256);
        float4 ev = e4[ln];
        float4 sv = ((const float4*)sbuf)[ln];
        float v = ev.x * sv.x + ev.y * sv.y + ev.z * sv.z + ev.w * sv.w;
#pragma unroll
        for (int off = 32; off >= 1; off >>= 1) v += __shfl_down(v, off);
        if (ln == 0) psis[j] = v + (eidx_sh[s] == 0 ? -1000.f : 0.f);
      }
      __syncthreads();                                 // B4
      if (tid == 0) {
        float mx = -3e38f;
        for (int j = 0; j < mc; j++) mx = fmaxf(mx, psis[j]);
        if (mx < -500.f) {       // all matches are pads -> reference cw == 0
          for (int j = 0; j < mc; j++) psis[j] = 0.f;
        } else {
          float ss = 0.f;
          for (int j = 0; j < mc; j++) { float e = expf(psis[j] - mx); psis[j] = e; ss += e; }
          float rs = 1.f / ss;
          for (int j = 0; j < mc; j++) psis[j] *= rs;
        }
      }
      __syncthreads();                                 // B5
      if (tid < 256) {
        ctxR = 0.f; ctxZ = 0.f; ctxN = 0.f;
        for (int j = 0; j < mc; j++) {
          float c = psis[j];
          const float* e = encih + (size_t)(b * 128 + mlist[j]) * 768;
          ctxR += c * e[h]; ctxZ += c * e[256 + h]; ctxN += c * e[512 + h];
        }
      }
    } else {
      if (tid < 256) { ctxR = 0.f; ctxZ = 0.f; ctxN = 0.f; }
    }
    __syncthreads();                                   // B6
  }
}

// psic = S32 x ENCSC^T (batched, block-diagonal) + pad mask. grid (32 b, 2 ny)
__global__ __launch_bounds__(256) void k_psic(const float* __restrict__ S32,
                                              const float* __restrict__ encsc,
                                              const int* __restrict__ encidx,
                                              float* __restrict__ psic) {
  int b = blockIdx.x, ny = blockIdx.y;
  int tid = threadIdx.x;
  int ti = tid & 15, tj = tid >> 4;
  int r0 = b * 64 + ti * 4;      // global (b,t) row
  int s0 = ny * 64 + tj * 4;
  const float4* A[4]; const float4* B[4];
#pragma unroll
  for (int i = 0; i < 4; i++) A[i] = (const float4*)(S32 + (size_t)(r0 + i) * 256);
#pragma unroll
  for (int j = 0; j < 4; j++) B[j] = (const float4*)(encsc + (size_t)(b * 128 + s0 + j) * 256);
  float acc[4][4];
#pragma unroll
  for (int i = 0; i < 4; i++)
#pragma unroll
    for (int j = 0; j < 4; j++) acc[i][j] = 0.f;
  for (int k = 0; k < 64; k++) {
    float4 a[4], bb[4];
#pragma unroll
    for (int i = 0; i < 4; i++) a[i] = A[i][k];
#pragma unroll
    for (int j = 0; j < 4; j++) bb[j] = B[j][k];
#pragma unroll
    for (int i = 0; i < 4; i++)
#pragma unroll
      for (int j = 0; j < 4; j++)
        acc[i][j] += a[i].x * bb[j].x + a[i].y * bb[j].y + a[i].z * bb[j].z + a[i].w * bb[j].w;
  }
#pragma unroll
  for (int i = 0; i < 4; i++)
#pragma unroll
    for (int j = 0; j < 4; j++) {
      float v = acc[i][j] + (encidx[b * 128 + s0 + j] == 0 ? -1000.f : 0.f);
      psic[(size_t)(r0 + i) * 128 + s0 + j] = v;
    }
}

// psi_g pass A: 128x128 bf16 MFMA tile -> per-row (max, sumexp) partials
__global__ __launch_bounds__(256) void k_p2a(const unsigned short* __restrict__ S16,
                                             const unsigned short* __restrict__ WG16,
                                             const float* __restrict__ wgb,
                                             float* __restrict__ pmax,
                                             float* __restrict__ psum) {
  __shared__ unsigned short lA[128 * 64];
  __shared__ unsigned short lB[128 * 64];
  __shared__ float redm[128][2];
  __shared__ float reds[128][2];
  int nc = blockIdx.x, mt = blockIdx.y;
  int tid = threadIdx.x;
  int wid = tid >> 6, lane = tid & 63;
  int wm = wid >> 1, wn = wid & 1;
  int quad = lane >> 4, l15 = lane & 15;
  f32x4_t acc[4][4];
#pragma unroll
  for (int i = 0; i < 4; i++)
#pragma unroll
    for (int j = 0; j < 4; j++) acc[i][j] = (f32x4_t){0.f, 0.f, 0.f, 0.f};
  for (int kt = 0; kt < 4; kt++) {
#pragma unroll
    for (int u = 0; u < 4; u++) {
      int c = u * 256 + tid;
      int row = c >> 3, ko = (c & 7) * 8;
      __builtin_amdgcn_global_load_lds(
          (const __attribute__((address_space(1))) unsigned int*)(S16 + (size_t)(mt * 128 + row) * 256 + kt * 64 + ko),
          (__attribute__((address_space(3))) unsigned int*)(lA + c * 8), 16, 0, 0);
      __builtin_amdgcn_global_load_lds(
          (const __attribute__((address_space(1))) unsigned int*)(WG16 + (size_t)(nc * 128 + row) * 256 + kt * 64 + ko),
          (__attribute__((address_space(3))) unsigned int*)(lB + c * 8), 16, 0, 0);
    }
    __syncthreads();
#pragma unroll
    for (int ks = 0; ks < 2; ks++) {
      bf16x8_t af[4], bfr[4];
#pragma unroll
      for (int i = 0; i < 4; i++) af[i] = *(const bf16x8_t*)(lA + (wm * 64 + i * 16 + l15) * 64 + ks * 32 + quad * 8);
#pragma unroll
      for (int j = 0; j < 4; j++) bfr[j] = *(const bf16x8_t*)(lB + (wn * 64 + j * 16 + l15) * 64 + ks * 32 + quad * 8);
#pragma unroll
      for (int i = 0; i < 4; i++)
#pragma unroll
        for (int j = 0; j < 4; j++)
          acc[i][j] = __builtin_amdgcn_mfma_f32_16x16x32_bf16(af[i], bfr[j], acc[i][j], 0, 0, 0);
    }
    __syncthreads();
  }
  float bj[4];
#pragma unroll
  for (int j = 0; j < 4; j++) bj[j] = wgb[nc * 128 + wn * 64 + j * 16 + l15];
#pragma unroll
  for (int i = 0; i < 4; i++) {
#pragma unroll
    for (int p = 0; p < 4; p++) {
      float m = -3e38f;
#pragma unroll
      for (int j = 0; j < 4; j++) m = fmaxf(m, acc[i][j][p] + bj[j]);
#pragma unroll
      for (int off = 1; off < 16; off <<= 1) m = fmaxf(m, __shfl_xor(m, off));
      float sum = 0.f;
#pragma unroll
      for (int j = 0; j < 4; j++) sum += expf(acc[i][j][p] + bj[j] - m);
#pragma unroll
      for (int off = 1; off < 16; off <<= 1) sum += __shfl_xor(sum, off);
      if (l15 == 0) {
        int row = wm * 64 + i * 16 + quad * 4 + p;
        redm[row][wn] = m;
        reds[row][wn] = sum;
      }
    }
  }
  __syncthreads();
  if (tid < 128) {
    float m0 = redm[tid][0], m1 = redm[tid][1];
    float M = fmaxf(m0, m1);
    float S = reds[tid][0] * expf(m0 - M) + reds[tid][1] * expf(m1 - M);
    int rg = mt * 128 + tid;
    pmax[(size_t)rg * 256 + nc] = M;
    psum[(size_t)rg * 256 + nc] = S;
  }
}

// merge 250 chunk partials + psi_c chunk (computed inline from psic) -> (M, Z)
__global__ __launch_bounds__(256) void k_p2m(const float* __restrict__ pmax,
                                             const float* __restrict__ psum,
                                             const float* __restrict__ psic,
                                             float* __restrict__ MZ) {
  __shared__ float rm[4], rs[4];
  __shared__ float cMs, cSs;
  __shared__ float Msh;
  int r = blockIdx.x, tid = threadIdx.x;
  // psi_c chunk partial over the 128 positions
  float pv = (tid < 128) ? psic[(size_t)r * 128 + tid] : -3e38f;
  float pm = pv;
#pragma unroll
  for (int off = 32; off >= 1; off >>= 1) pm = fmaxf(pm, __shfl_xor(pm, off));
  if (tid < 128 && (tid & 63) == 0) rm[tid >> 6] = pm;
  __syncthreads();
  float cMv = fmaxf(rm[0], rm[1]);
  float pe = (tid < 128) ? expf(pv - cMv) : 0.f;
#pragma unroll
  for (int off = 32; off >= 1; off >>= 1) pe += __shfl_xor(pe, off);
  if (tid < 128 && (tid & 63) == 0) rs[tid >> 6] = pe;
  __syncthreads();
  if (tid == 0) { cMs = cMv; cSs = rs[0] + rs[1]; }
  __syncthreads();
  // merge 250 MFMA-chunk partials + the psi_c chunk
  float m = (tid < 250) ? pmax[(size_t)r * 256 + tid] : ((tid == 250) ? cMs : -3e38f);
  float mm = m;
#pragma unroll
  for (int off = 32; off >= 1; off >>= 1) mm = fmaxf(mm, __shfl_xor(mm, off));
  if ((tid & 63) == 0) rm[tid >> 6] = mm;
  __syncthreads();
  if (tid == 0) Msh = fmaxf(fmaxf(rm[0], rm[1]), fmaxf(rm[2], rm[3]));
  __syncthreads();
  float M = Msh;
  float zv = (tid < 250) ? psum[(size_t)r * 256 + tid] : ((tid == 250) ? cSs : 0.f);
  float z = zv * expf(m - M);
#pragma unroll
  for (int off = 32; off >= 1; off >>= 1) z += __shfl_xor(z, off);
  if ((tid & 63) == 0) rs[tid >> 6] = z;
  __syncthreads();
  if (tid == 0) {
    MZ[2 * r] = M;
    MZ[2 * r + 1] = rs[0] + rs[1] + rs[2] + rs[3];
  }
}

// pass B: recompute psi_g tile, p = exp(psi-M)/Z, write out; chunk-local scatter
__global__ __launch_bounds__(256) void k_p2b(const unsigned short* __restrict__ S16,
                                             const unsigned short* __restrict__ WG16,
                                             const float* __restrict__ wgb,
                                             const float* __restrict__ MZ,
                                             const float* __restrict__ psic,
                                             const int* __restrict__ encidx,
                                             float* __restrict__ outp) {
  int nc = blockIdx.x, mt = blockIdx.y;
  int tid = threadIdx.x;
  if (nc == 250) {  // OOV columns [32000, 32100)
    for (int p = tid; p < 128 * 100; p += 256) {
      int rl = p / 100, c2 = p - rl * 100;
      int rg = mt * 128 + rl;
      outp[(size_t)rg * VT_ + 32000 + c2] = 1e-4f;
    }
    __syncthreads();
    if (tid < 128) {
      int rg = mt * 128 + tid, b = rg >> 6;
      float M = MZ[2 * rg];
      float iZ = 1.f / MZ[2 * rg + 1];
      for (int s = 0; s < 128; s++) {
        int idx = encidx[b * 128 + s];
        if (idx >= 32000) {
          float v = expf(psic[(size_t)rg * 128 + s] - M) * iZ;
          outp[(size_t)rg * VT_ + idx] += v;
        }
      }
    }
    return;
  }
  __shared__ unsigned short lA[128 * 64];
  __shared__ unsigned short lB[128 * 64];
  int wid = tid >> 6, lane = tid & 63;
  int wm = wid >> 1, wn = wid & 1;
  int quad = lane >> 4, l15 = lane & 15;
  f32x4_t acc[4][4];
#pragma unroll
  for (int i = 0; i < 4; i++)
#pragma unroll
    for (int j = 0; j < 4; j++) acc[i][j] = (f32x4_t){0.f, 0.f, 0.f, 0.f};
  for (int kt = 0; kt < 4; kt++) {
#pragma unroll
    for (int u = 0; u < 4; u++) {
      int c = u * 256 + tid;
      int row = c >> 3, ko = (c & 7) * 8;
      __builtin_amdgcn_global_load_lds(
          (const __attribute__((address_space(1))) unsigned int*)(S16 + (size_t)(mt * 128 + row) * 256 + kt * 64 + ko),
          (__attribute__((address_space(3))) unsigned int*)(lA + c * 8), 16, 0, 0);
      __builtin_amdgcn_global_load_lds(
          (const __attribute__((address_space(1))) unsigned int*)(WG16 + (size_t)(nc * 128 + row) * 256 + kt * 64 + ko),
          (__attribute__((address_space(3))) unsigned int*)(lB + c * 8), 16, 0, 0);
    }
    __syncthreads();
#pragma unroll
    for (int ks = 0; ks < 2; ks++) {
      bf16x8_t af[4], bfr[4];
#pragma unroll
      for (int i = 0; i < 4; i++) af[i] = *(const bf16x8_t*)(lA + (wm * 64 + i * 16 + l15) * 64 + ks * 32 + quad * 8);
#pragma unroll
      for (int j = 0; j < 4; j++) bfr[j] = *(const bf16x8_t*)(lB + (wn * 64 + j * 16 + l15) * 64 + ks * 32 + quad * 8);
#pragma unroll
      for (int i = 0; i < 4; i++)
#pragma unroll
        for (int j = 0; j < 4; j++)
          acc[i][j] = __builtin_amdgcn_mfma_f32_16x16x32_bf16(af[i], bfr[j], acc[i][j], 0, 0, 0);
    }
    __syncthreads();
  }
  float bj[4];
#pragma unroll
  for (int j = 0; j < 4; j++) bj[j] = wgb[nc * 128 + wn * 64 + j * 16 + l15];
#pragma unroll
  for (int i = 0; i < 4; i++) {
#pragma unroll
    for (int p = 0; p < 4; p++) {
      int rg = mt * 128 + wm * 64 + i * 16 + quad * 4 + p;
      float M = MZ[2 * rg];
      float iZ = 1.f / MZ[2 * rg + 1];
      size_t base = (size_t)rg * VT_ + nc * 128 + wn * 64 + l15;
#pragma unroll
      for (int j = 0; j < 4; j++)
        outp[base + j * 16] = expf(acc[i][j][p] + bj[j] - M) * iZ;
    }
  }
  __syncthreads();
  int nlo = nc * 128, nhi = nlo + 128;
  if (tid < 128) {
    int rg = mt * 128 + tid, b = rg >> 6;
    float M = MZ[2 * rg];
    float iZ = 1.f / MZ[2 * rg + 1];
    for (int s = 0; s < 128; s++) {
      int idx = encidx[b * 128 + s];
      if (idx >= nlo && idx < nhi) {
        float v = expf(psic[(size_t)rg * 128 + s] - M) * iZ;
        outp[(size_t)rg * VT_ + idx] += v;
      }
    }
  }
}

// ---------------------------------------------------------------- launch
extern "C" void kernel_launch(void* const* d_in, const int* in_sizes, int n_in,
                              void* d_out, int out_size, void* d_ws, size_t ws_size,
                              hipStream_t stream) {
  (void)in_sizes; (void)n_in; (void)out_size; (void)ws_size;
  const int*   inputs  = (const int*)d_in[0];
  const float* encoded = (const float*)d_in[1];
  const int*   encidx  = (const int*)d_in[2];
  const float* bridge  = (const float*)d_in[3];
  const float* embed   = (const float*)d_in[4];
  const float* wih     = (const float*)d_in[5];
  const float* whh     = (const float*)d_in[6];
  const float* bih     = (const float*)d_in[7];
  const float* bhh     = (const float*)d_in[8];
  const float* wg      = (const float*)d_in[9];
  const float* wgb     = (const float*)d_in[10];
  const float* wo      = (const float*)d_in[11];
  const float* wob     = (const float*)d_in[12];
  float* out = (float*)d_out;

  char* ws = (char*)d_ws;
  size_t off = 0;
  auto alloc = [&](size_t bytes) -> void* {
    void* p = ws + off;
    off += (bytes + 255) & ~(size_t)255;
    return p;
  };
  unsigned short* WG16 = (unsigned short*)alloc((size_t)32000 * 256 * 2);
  unsigned short* WHH16 = (unsigned short*)alloc((size_t)768 * 256 * 2);
  float* S32           = (float*)alloc((size_t)2048 * 256 * 4);
  unsigned short* S16  = (unsigned short*)alloc((size_t)2048 * 256 * 2);
  float* ENCSC         = (float*)alloc((size_t)4096 * 256 * 4);
  float* ENCIH         = (float*)alloc((size_t)4096 * 768 * 4);
  float* XG            = (float*)alloc((size_t)2048 * 768 * 4);
  float* S0            = (float*)alloc((size_t)32 * 256 * 4);
  float* PSIC          = (float*)alloc((size_t)2048 * 128 * 4);
  float* PMAX          = (float*)alloc((size_t)2048 * 256 * 4);
  float* PSUM          = (float*)alloc((size_t)2048 * 256 * 4);
  float* MZ            = (float*)alloc((size_t)2048 * 2 * 4);

  k_conv<<<1024, 256, 0, stream>>>(wg, WG16, 32000 * 256 / 4);
  k_conv<<<192, 256, 0, stream>>>(whh, WHH16, 768 * 256 / 4);
  k_enc<<<dim3(64, 4), 256, 0, stream>>>(encoded, wo, wob, ENCSC);
  k_s0<<<32, 256, 0, stream>>>(encoded, bridge, S0);
  k_xg<<<dim3(32, 12), 256, 0, stream>>>(embed, inputs, wih, bih, XG);
  k_encih<<<4096, 256, 0, stream>>>(encoded, wih, encidx, inputs, ENCIH);
  k_seq<<<32, 768, 0, stream>>>(WHH16, bhh, XG, ENCSC, ENCIH, encidx, inputs, S0, S32, S16);
  k_psic<<<dim3(32, 2), 256, 0, stream>>>(S32, ENCSC, encidx, PSIC);
  k_p2a<<<dim3(250, 16), 256, 0, stream>>>(S16, WG16, wgb, PMAX, PSUM);
  k_p2m<<<2048, 256, 0, stream>>>(PMAX, PSUM, PSIC, MZ);
  k_p2b<<<dim3(251, 16), 256, 0, stream>>>(S16, WG16, wgb, MZ, PSIC, encidx, out);
}

// Round 2
// 913.884 us; speedup vs baseline: 1.3589x; 1.1462x over previous
//
#include <hip/hip_runtime.h>
#include <math.h>
#include <stdint.h>

// Problem constants
static const int VOC  = 32000;
static const int VT_  = 32100;

typedef __attribute__((ext_vector_type(8))) short bf16x8_t;
typedef __attribute__((ext_vector_type(4))) float f32x4_t;

__device__ __forceinline__ unsigned short f2bf(float f) {
  union { float f; unsigned int u; } v; v.f = f;
  unsigned int u = v.u;
  u = u + 0x7FFFu + ((u >> 16) & 1u);   // RNE
  return (unsigned short)(u >> 16);
}
__device__ __forceinline__ float bf2f(unsigned short u) {
  union { unsigned int i; float f; } w; w.i = ((unsigned int)u) << 16; return w.f;
}
__device__ __forceinline__ float bfbits(unsigned int u) {
  union { unsigned int i; float f; } w; w.i = u; return w.f;
}

// ---------------------------------------------------------------- utilities
__global__ void k_conv(const float* __restrict__ src, unsigned short* __restrict__ dst, int n4) {
  int i = blockIdx.x * blockDim.x + threadIdx.x;
  int stride = gridDim.x * blockDim.x;
  for (; i < n4; i += stride) {
    float4 f = ((const float4*)src)[i];
    ushort4 o;
    o.x = f2bf(f.x); o.y = f2bf(f.y); o.z = f2bf(f.z); o.w = f2bf(f.w);
    ((ushort4*)dst)[i] = o;
  }
}

// enc_scores = tanh(encoded @ Wo^T + Wo_b): M=4096 (b,s), N=256, K=512
__global__ __launch_bounds__(256) void k_enc(const float* __restrict__ enc,
                                             const float* __restrict__ wo,
                                             const float* __restrict__ wob,
                                             float* __restrict__ outp) {
  int bm = blockIdx.x, bn = blockIdx.y;
  int tid = threadIdx.x;
  int ti = tid & 15, tj = tid >> 4;
  int r0 = bm * 64 + ti * 4;
  int n0 = bn * 64 + tj * 4;
  const float4* A[4]; const float4* B[4];
#pragma unroll
  for (int i = 0; i < 4; i++) A[i] = (const float4*)(enc + (size_t)(r0 + i) * 512);
#pragma unroll
  for (int j = 0; j < 4; j++) B[j] = (const float4*)(wo + (size_t)(n0 + j) * 512);
  float acc[4][4];
#pragma unroll
  for (int i = 0; i < 4; i++)
#pragma unroll
    for (int j = 0; j < 4; j++) acc[i][j] = 0.f;
  for (int k = 0; k < 128; k++) {
    float4 a[4], b[4];
#pragma unroll
    for (int i = 0; i < 4; i++) a[i] = A[i][k];
#pragma unroll
    for (int j = 0; j < 4; j++) b[j] = B[j][k];
#pragma unroll
    for (int i = 0; i < 4; i++)
#pragma unroll
      for (int j = 0; j < 4; j++)
        acc[i][j] += a[i].x * b[j].x + a[i].y * b[j].y + a[i].z * b[j].z + a[i].w * b[j].w;
  }
#pragma unroll
  for (int i = 0; i < 4; i++)
#pragma unroll
    for (int j = 0; j < 4; j++)
      outp[(size_t)(r0 + i) * 256 + n0 + j] = tanhf(acc[i][j] + wob[n0 + j]);
}

// Xg = embed[inputs] @ Wih[:, :256]^T + b_ih: M=2048, N=768, K=256
__global__ __launch_bounds__(256) void k_xg(const float* __restrict__ embed,
                                            const int* __restrict__ inputs,
                                            const float* __restrict__ wih,
                                            const float* __restrict__ bih,
                                            float* __restrict__ xg) {
  int bm = blockIdx.x, bn = blockIdx.y;
  int tid = threadIdx.x;
  int ti = tid & 15, tj = tid >> 4;
  int r0 = bm * 64 + ti * 4;
  int n0 = bn * 64 + tj * 4;
  const float4* A[4]; const float4* B[4];
#pragma unroll
  for (int i = 0; i < 4; i++) A[i] = (const float4*)(embed + (size_t)inputs[r0 + i] * 256);
#pragma unroll
  for (int j = 0; j < 4; j++) B[j] = (const float4*)(wih + (size_t)(n0 + j) * 768);
  float acc[4][4];
#pragma unroll
  for (int i = 0; i < 4; i++)
#pragma unroll
    for (int j = 0; j < 4; j++) acc[i][j] = 0.f;
  for (int k = 0; k < 64; k++) {
    float4 a[4], b[4];
#pragma unroll
    for (int i = 0; i < 4; i++) a[i] = A[i][k];
#pragma unroll
    for (int j = 0; j < 4; j++) b[j] = B[j][k];
#pragma unroll
    for (int i = 0; i < 4; i++)
#pragma unroll
      for (int j = 0; j < 4; j++)
        acc[i][j] += a[i].x * b[j].x + a[i].y * b[j].y + a[i].z * b[j].z + a[i].w * b[j].w;
  }
#pragma unroll
  for (int i = 0; i < 4; i++)
#pragma unroll
    for (int j = 0; j < 4; j++)
      xg[(size_t)(r0 + i) * 768 + n0 + j] = acc[i][j] + bih[n0 + j];
}

// s0 = encoded[:, -1, :] @ bridge^T
__global__ __launch_bounds__(256) void k_s0(const float* __restrict__ enc,
                                            const float* __restrict__ bw,
                                            float* __restrict__ s0) {
  int b = blockIdx.x, h = threadIdx.x;
  const float4* a4 = (const float4*)(enc + ((size_t)b * 128 + 127) * 512);
  const float4* w4 = (const float4*)(bw + (size_t)h * 512);
  float acc = 0.f;
  for (int k = 0; k < 128; k++) {
    float4 a = a4[k], w = w4[k];
    acc += a.x * w.x + a.y * w.y + a.z * w.z + a.w * w.w;
  }
  s0[b * 256 + h] = acc;
}

// ENC_ih[b,s,:] = encoded[b,s,:] @ Wih[:, 256:768]^T  -- only where token ever matches
__global__ __launch_bounds__(256) void k_encih(const float* __restrict__ enc,
                                               const float* __restrict__ wih,
                                               const int* __restrict__ encidx,
                                               const int* __restrict__ inputs,
                                               float* __restrict__ encih) {
  __shared__ int flag;
  int bs = blockIdx.x;
  int b = bs >> 7;
  int tid = threadIdx.x;
  int idx = encidx[bs];
  if (tid < 64) {
    unsigned long long m = __ballot(inputs[b * 64 + tid] == idx);
    if (tid == 0) flag = (m != 0ULL);
  }
  __syncthreads();
  if (!flag) return;
  const float4* e4 = (const float4*)(enc + (size_t)bs * 512);
  for (int d = tid; d < 768; d += 256) {
    const float4* w4 = (const float4*)(wih + (size_t)d * 768 + 256);
    float acc = 0.f;
    for (int k = 0; k < 128; k++) {
      float4 e = e4[k], w = w4[k];
      acc += e.x * w.x + e.y * w.y + e.z * w.z + e.w * w.w;
    }
    encih[(size_t)bs * 768 + d] = acc;
  }
}

// -------------------------------------------------------- sequential GRU
// One block per batch row b: 768 threads = 12 waves.
// W_hh bf16 [768][256]; each wave owns 64 output columns (full K).
// K-chunks 0..5 (k in [0,192)) live in VGPRs (24 bf16x8 frags = 96 VGPR/lane;
// 12 waves x 64 lanes x 96 regs = 294 KB = exactly that slice of W).
// K-chunks 6..7 (k in [192,256), 98 KB) live in LDS, XOR-swizzled so the
// 16-lane row-gather is 2-way (free) instead of 16-way conflicted.
// => ZERO global weight traffic inside the 64-step loop (was 393 KB/step,
// the measured per-step floor). All per-step state is block-local.
__global__ __launch_bounds__(768, 1) void k_seq(
    const unsigned short* __restrict__ whb,  // [768][256] bf16 W_hh
    const float* __restrict__ bhh,
    const float* __restrict__ xg, const float* __restrict__ encsc,
    const float* __restrict__ encih, const int* __restrict__ encidx,
    const int* __restrict__ inputs, const float* __restrict__ s0,
    float* __restrict__ S32, unsigned short* __restrict__ S16) {
  __shared__ float sbuf[256];
  __shared__ __align__(16) unsigned short sb16[256];
  __shared__ float ghp[768];
  __shared__ float psis[128];
  __shared__ int mlist[128];
  __shared__ int eidx_sh[128];
  __shared__ int inp_sh[64];
  __shared__ int mcnt_sh;
  __shared__ __align__(16) unsigned short wlds[768 * 64];  // 96 KB, k-chunks 6..7
  int b = blockIdx.x;
  int tid = threadIdx.x;
  int wid = tid >> 6, lane = tid & 63;
  int quad = lane >> 4, l15 = lane & 15;
  int n0 = wid * 64;                 // this wave's 64 output columns
  int h = tid;                       // gate thread id (tid<256)
  // --- stage k in [192,256) into LDS, swizzled: slot ch holds global chunk ch^(row&7)
  for (int c2 = tid; c2 < 6144; c2 += 768) {
    int row = c2 >> 3, ch = c2 & 7;
    int gch = ch ^ (row & 7);
    int4 v = *(const int4*)(whb + (size_t)row * 256 + 192 + gch * 8);
    *(int4*)(wlds + row * 64 + ch * 8) = v;
  }
  // --- preload k in [0,192) into VGPRs
  bf16x8_t wf[24];
#pragma unroll
  for (int c = 0; c < 4; c++)
#pragma unroll
    for (int kt = 0; kt < 6; kt++)
      wf[c * 6 + kt] = *(const bf16x8_t*)(whb + (size_t)(n0 + c * 16 + l15) * 256 + kt * 32 + quad * 8);
  float bR = 0.f, bZ = 0.f, bN = 0.f, ctxR = 0.f, ctxZ = 0.f, ctxN = 0.f;
  if (tid < 256) {
    bR = bhh[h]; bZ = bhh[256 + h]; bN = bhh[512 + h];
    float v = s0[b * 256 + tid];
    sbuf[tid] = v;
    sb16[tid] = f2bf(v);
  }
  if (tid < 128) eidx_sh[tid] = encidx[b * 128 + tid];
  if (tid < 64) inp_sh[tid] = inputs[b * 64 + tid];
  __syncthreads();
  for (int t = 0; t < 64; t++) {
    int r = b * 64 + t;
    // --- gh = s @ W_hh^T via MFMA (A = broadcast s-row; C row0 = s@W^T)
    f32x4_t a0 = {0.f,0.f,0.f,0.f}, a1 = {0.f,0.f,0.f,0.f};
    f32x4_t a2 = {0.f,0.f,0.f,0.f}, a3 = {0.f,0.f,0.f,0.f};
#pragma unroll
    for (int kt = 0; kt < 6; kt++) {
      bf16x8_t af = *(const bf16x8_t*)(sb16 + kt * 32 + quad * 8);
      a0 = __builtin_amdgcn_mfma_f32_16x16x32_bf16(af, wf[ 0 + kt], a0, 0, 0, 0);
      a1 = __builtin_amdgcn_mfma_f32_16x16x32_bf16(af, wf[ 6 + kt], a1, 0, 0, 0);
      a2 = __builtin_amdgcn_mfma_f32_16x16x32_bf16(af, wf[12 + kt], a2, 0, 0, 0);
      a3 = __builtin_amdgcn_mfma_f32_16x16x32_bf16(af, wf[18 + kt], a3, 0, 0, 0);
    }
#pragma unroll
    for (int kt2 = 0; kt2 < 2; kt2++) {
      bf16x8_t af = *(const bf16x8_t*)(sb16 + (6 + kt2) * 32 + quad * 8);
      int slot = ((kt2 * 4 + quad) ^ (l15 & 7)) * 8;
      bf16x8_t b0 = *(const bf16x8_t*)(wlds + (n0 +  0 + l15) * 64 + slot);
      bf16x8_t b1 = *(const bf16x8_t*)(wlds + (n0 + 16 + l15) * 64 + slot);
      bf16x8_t b2 = *(const bf16x8_t*)(wlds + (n0 + 32 + l15) * 64 + slot);
      bf16x8_t b3 = *(const bf16x8_t*)(wlds + (n0 + 48 + l15) * 64 + slot);
      a0 = __builtin_amdgcn_mfma_f32_16x16x32_bf16(af, b0, a0, 0, 0, 0);
      a1 = __builtin_amdgcn_mfma_f32_16x16x32_bf16(af, b1, a1, 0, 0, 0);
      a2 = __builtin_amdgcn_mfma_f32_16x16x32_bf16(af, b2, a2, 0, 0, 0);
      a3 = __builtin_amdgcn_mfma_f32_16x16x32_bf16(af, b3, a3, 0, 0, 0);
    }
    if (lane < 16) {
      ghp[n0 +      lane] = a0[0];
      ghp[n0 + 16 + lane] = a1[0];
      ghp[n0 + 32 + lane] = a2[0];
      ghp[n0 + 48 + lane] = a3[0];
    }
    __syncthreads();                                   // B1: gh complete
    if (tid < 256) {
      float hr = ghp[h] + bR;
      float hz = ghp[256 + h] + bZ;
      float hn = ghp[512 + h] + bN;
      const float* xr = xg + (size_t)r * 768;
      float gr = xr[h] + ctxR;
      float gz = xr[256 + h] + ctxZ;
      float gn = xr[512 + h] + ctxN;
      float rgate = 1.f / (1.f + expf(-(gr + hr)));
      float zgate = 1.f / (1.f + expf(-(gz + hz)));
      float ngate = tanhf(gn + rgate * hn);
      float sold = sbuf[h];
      float snew = (1.f - zgate) * ngate + zgate * sold;
      S32[(size_t)r * 256 + h] = snew;
      S16[(size_t)r * 256 + h] = f2bf(snew);
      sbuf[h] = snew;                                  // own-element RMW, safe
      sb16[h] = f2bf(snew);
    }
    if (tid == 256) mcnt_sh = 0;
    __syncthreads();                                   // B2: s_t complete
    if (t == 63) break;
    // --- matched-position copy-attention for ctx(t) -> used at step t+1
    int inp_t = inp_sh[t];
    if (tid < 128 && eidx_sh[tid] == inp_t) {
      int p = atomicAdd(&mcnt_sh, 1);
      mlist[p] = tid;
    }
    __syncthreads();                                   // B3
    int mc = mcnt_sh;
    if (mc > 0) {
      int wv = tid >> 6, ln = tid & 63;
      for (int j = wv; j < mc; j += 12) {
        int s = mlist[j];
        const float4* e4 = (const float4*)(encsc + (size_t)(b * 128 + s) * 256);
        float4 ev = e4[ln];
        float4 sv = ((const float4*)sbuf)[ln];
        float v = ev.x * sv.x + ev.y * sv.y + ev.z * sv.z + ev.w * sv.w;
#pragma unroll
        for (int off = 32; off >= 1; off >>= 1) v += __shfl_down(v, off);
        if (ln == 0) psis[j] = v + (eidx_sh[s] == 0 ? -1000.f : 0.f);
      }
      __syncthreads();                                 // B4
      if (tid == 0) {
        float mx = -3e38f;
        for (int j = 0; j < mc; j++) mx = fmaxf(mx, psis[j]);
        if (mx < -500.f) {       // all matches are pads -> reference cw == 0
          for (int j = 0; j < mc; j++) psis[j] = 0.f;
        } else {
          float ss = 0.f;
          for (int j = 0; j < mc; j++) { float e = expf(psis[j] - mx); psis[j] = e; ss += e; }
          float rs = 1.f / ss;
          for (int j = 0; j < mc; j++) psis[j] *= rs;
        }
      }
      __syncthreads();                                 // B5
      if (tid < 256) {
        ctxR = 0.f; ctxZ = 0.f; ctxN = 0.f;
        for (int j = 0; j < mc; j++) {
          float c = psis[j];
          const float* e = encih + (size_t)(b * 128 + mlist[j]) * 768;
          ctxR += c * e[h]; ctxZ += c * e[256 + h]; ctxN += c * e[512 + h];
        }
      }
    } else {
      if (tid < 256) { ctxR = 0.f; ctxZ = 0.f; ctxN = 0.f; }
    }
    __syncthreads();                                   // B6
  }
}

// psic = S32 x ENCSC^T (batched, block-diagonal) + pad mask. grid (32 b, 2 ny)
__global__ __launch_bounds__(256) void k_psic(const float* __restrict__ S32,
                                              const float* __restrict__ encsc,
                                              const int* __restrict__ encidx,
                                              float* __restrict__ psic) {
  int b = blockIdx.x, ny = blockIdx.y;
  int tid = threadIdx.x;
  int ti = tid & 15, tj = tid >> 4;
  int r0 = b * 64 + ti * 4;      // global (b,t) row
  int s0 = ny * 64 + tj * 4;
  const float4* A[4]; const float4* B[4];
#pragma unroll
  for (int i = 0; i < 4; i++) A[i] = (const float4*)(S32 + (size_t)(r0 + i) * 256);
#pragma unroll
  for (int j = 0; j < 4; j++) B[j] = (const float4*)(encsc + (size_t)(b * 128 + s0 + j) * 256);
  float acc[4][4];
#pragma unroll
  for (int i = 0; i < 4; i++)
#pragma unroll
    for (int j = 0; j < 4; j++) acc[i][j] = 0.f;
  for (int k = 0; k < 64; k++) {
    float4 a[4], bb[4];
#pragma unroll
    for (int i = 0; i < 4; i++) a[i] = A[i][k];
#pragma unroll
    for (int j = 0; j < 4; j++) bb[j] = B[j][k];
#pragma unroll
    for (int i = 0; i < 4; i++)
#pragma unroll
      for (int j = 0; j < 4; j++)
        acc[i][j] += a[i].x * bb[j].x + a[i].y * bb[j].y + a[i].z * bb[j].z + a[i].w * bb[j].w;
  }
#pragma unroll
  for (int i = 0; i < 4; i++)
#pragma unroll
    for (int j = 0; j < 4; j++) {
      float v = acc[i][j] + (encidx[b * 128 + s0 + j] == 0 ? -1000.f : 0.f);
      psic[(size_t)(r0 + i) * 128 + s0 + j] = v;
    }
}

// psi_g pass A: 128x128 bf16 MFMA tile -> per-row (max, sumexp) partials.
// STORE_PSI: also writes bf16 psi (rounded) to PSI16; partials are computed
// from the ROUNDED values so pass B's exp(psi-M)/Z is self-consistent.
// LDS tiles XOR-swizzled (source-side for global_load_lds, matching reads).
template <bool STORE_PSI>
__global__ __launch_bounds__(256) void k_p2a(const unsigned short* __restrict__ S16,
                                             const unsigned short* __restrict__ WG16,
                                             const float* __restrict__ wgb,
                                             float* __restrict__ pmax,
                                             float* __restrict__ psum,
                                             unsigned short* __restrict__ psi16) {
  __shared__ unsigned short lA[128 * 64];
  __shared__ unsigned short lB[128 * 64];
  __shared__ float redm[128][2];
  __shared__ float reds[128][2];
  int nc = blockIdx.x, mt = blockIdx.y;
  int tid = threadIdx.x;
  int wid = tid >> 6, lane = tid & 63;
  int wm = wid >> 1, wn = wid & 1;
  int quad = lane >> 4, l15 = lane & 15;
  f32x4_t acc[4][4];
#pragma unroll
  for (int i = 0; i < 4; i++)
#pragma unroll
    for (int j = 0; j < 4; j++) acc[i][j] = (f32x4_t){0.f, 0.f, 0.f, 0.f};
  for (int kt = 0; kt < 4; kt++) {
#pragma unroll
    for (int u = 0; u < 4; u++) {
      int c = u * 256 + tid;
      int row = c >> 3;
      int ko = ((c & 7) ^ (row & 7)) * 8;   // swizzled source chunk
      __builtin_amdgcn_global_load_lds(
          (const __attribute__((address_space(1))) unsigned int*)(S16 + (size_t)(mt * 128 + row) * 256 + kt * 64 + ko),
          (__attribute__((address_space(3))) unsigned int*)(lA + c * 8), 16, 0, 0);
      __builtin_amdgcn_global_load_lds(
          (const __attribute__((address_space(1))) unsigned int*)(WG16 + (size_t)(nc * 128 + row) * 256 + kt * 64 + ko),
          (__attribute__((address_space(3))) unsigned int*)(lB + c * 8), 16, 0, 0);
    }
    __syncthreads();
#pragma unroll
    for (int ks = 0; ks < 2; ks++) {
      bf16x8_t af[4], bfr[4];
      int slot = ((ks * 4 + quad) ^ (l15 & 7)) * 8;
#pragma unroll
      for (int i = 0; i < 4; i++) af[i] = *(const bf16x8_t*)(lA + (wm * 64 + i * 16 + l15) * 64 + slot);
#pragma unroll
      for (int j = 0; j < 4; j++) bfr[j] = *(const bf16x8_t*)(lB + (wn * 64 + j * 16 + l15) * 64 + slot);
#pragma unroll
      for (int i = 0; i < 4; i++)
#pragma unroll
        for (int j = 0; j < 4; j++)
          acc[i][j] = __builtin_amdgcn_mfma_f32_16x16x32_bf16(af[i], bfr[j], acc[i][j], 0, 0, 0);
    }
    __syncthreads();
  }
  float bj[4];
#pragma unroll
  for (int j = 0; j < 4; j++) bj[j] = wgb[nc * 128 + wn * 64 + j * 16 + l15];
#pragma unroll
  for (int i = 0; i < 4; i++) {
#pragma unroll
    for (int p = 0; p < 4; p++) {
      int rg = mt * 128 + wm * 64 + i * 16 + quad * 4 + p;
      float rv[4];
#pragma unroll
      for (int j = 0; j < 4; j++) {
        float val = acc[i][j][p] + bj[j];
        unsigned short us = f2bf(val);
        rv[j] = bf2f(us);
        if constexpr (STORE_PSI)
          psi16[(size_t)rg * 32000 + nc * 128 + wn * 64 + j * 16 + l15] = us;
      }
      float m = -3e38f;
#pragma unroll
      for (int j = 0; j < 4; j++) m = fmaxf(m, rv[j]);
#pragma unroll
      for (int off = 1; off < 16; off <<= 1) m = fmaxf(m, __shfl_xor(m, off));
      float sum = 0.f;
#pragma unroll
      for (int j = 0; j < 4; j++) sum += expf(rv[j] - m);
#pragma unroll
      for (int off = 1; off < 16; off <<= 1) sum += __shfl_xor(sum, off);
      if (l15 == 0) {
        int row = wm * 64 + i * 16 + quad * 4 + p;
        redm[row][wn] = m;
        reds[row][wn] = sum;
      }
    }
  }
  __syncthreads();
  if (tid < 128) {
    float m0 = redm[tid][0], m1 = redm[tid][1];
    float M = fmaxf(m0, m1);
    float S = reds[tid][0] * expf(m0 - M) + reds[tid][1] * expf(m1 - M);
    int rg = mt * 128 + tid;
    pmax[(size_t)rg * 256 + nc] = M;
    psum[(size_t)rg * 256 + nc] = S;
  }
}

// merge 250 chunk partials + psi_c chunk (computed inline from psic) -> (M, Z)
__global__ __launch_bounds__(256) void k_p2m(const float* __restrict__ pmax,
                                             const float* __restrict__ psum,
                                             const float* __restrict__ psic,
                                             float* __restrict__ MZ) {
  __shared__ float rm[4], rs[4];
  __shared__ float cMs, cSs;
  __shared__ float Msh;
  int r = blockIdx.x, tid = threadIdx.x;
  // psi_c chunk partial over the 128 positions
  float pv = (tid < 128) ? psic[(size_t)r * 128 + tid] : -3e38f;
  float pm = pv;
#pragma unroll
  for (int off = 32; off >= 1; off >>= 1) pm = fmaxf(pm, __shfl_xor(pm, off));
  if (tid < 128 && (tid & 63) == 0) rm[tid >> 6] = pm;
  __syncthreads();
  float cMv = fmaxf(rm[0], rm[1]);
  float pe = (tid < 128) ? expf(pv - cMv) : 0.f;
#pragma unroll
  for (int off = 32; off >= 1; off >>= 1) pe += __shfl_xor(pe, off);
  if (tid < 128 && (tid & 63) == 0) rs[tid >> 6] = pe;
  __syncthreads();
  if (tid == 0) { cMs = cMv; cSs = rs[0] + rs[1]; }
  __syncthreads();
  // merge 250 MFMA-chunk partials + the psi_c chunk
  float m = (tid < 250) ? pmax[(size_t)r * 256 + tid] : ((tid == 250) ? cMs : -3e38f);
  float mm = m;
#pragma unroll
  for (int off = 32; off >= 1; off >>= 1) mm = fmaxf(mm, __shfl_xor(mm, off));
  if ((tid & 63) == 0) rm[tid >> 6] = mm;
  __syncthreads();
  if (tid == 0) Msh = fmaxf(fmaxf(rm[0], rm[1]), fmaxf(rm[2], rm[3]));
  __syncthreads();
  float M = Msh;
  float zv = (tid < 250) ? psum[(size_t)r * 256 + tid] : ((tid == 250) ? cSs : 0.f);
  float z = zv * expf(m - M);
#pragma unroll
  for (int off = 32; off >= 1; off >>= 1) z += __shfl_xor(z, off);
  if ((tid & 63) == 0) rs[tid >> 6] = z;
  __syncthreads();
  if (tid == 0) {
    MZ[2 * r] = M;
    MZ[2 * r + 1] = rs[0] + rs[1] + rs[2] + rs[3];
  }
}

// pass B (streaming): p = exp(psi16 - M)/Z -> out; OOV fill + per-row scatter.
// One block per output row. Fully coalesced 16B loads / 2x16B stores.
__global__ __launch_bounds__(256) void k_pb(const unsigned short* __restrict__ psi16,
                                            const float* __restrict__ MZ,
                                            const float* __restrict__ psic,
                                            const int* __restrict__ encidx,
                                            float* __restrict__ outp) {
  int r = blockIdx.x;          // 0..2047
  int b = r >> 6;
  int tid = threadIdx.x;
  float M = MZ[2 * r];
  float iZ = 1.f / MZ[2 * r + 1];
  const unsigned short* prow = psi16 + (size_t)r * 32000;
  float* orow = outp + (size_t)r * VT_;
#pragma unroll 2
  for (int i = 0; i < 16; i++) {
    int c0 = (i * 256 + tid) * 8;
    if (c0 < 32000) {
      int4 v = *(const int4*)(prow + c0);
      float4 o0, o1;
      unsigned int x;
      x = (unsigned int)v.x;
      o0.x = expf(bfbits(x << 16) - M) * iZ;
      o0.y = expf(bfbits(x & 0xffff0000u) - M) * iZ;
      x = (unsigned int)v.y;
      o0.z = expf(bfbits(x << 16) - M) * iZ;
      o0.w = expf(bfbits(x & 0xffff0000u) - M) * iZ;
      x = (unsigned int)v.z;
      o1.x = expf(bfbits(x << 16) - M) * iZ;
      o1.y = expf(bfbits(x & 0xffff0000u) - M) * iZ;
      x = (unsigned int)v.w;
      o1.z = expf(bfbits(x << 16) - M) * iZ;
      o1.w = expf(bfbits(x & 0xffff0000u) - M) * iZ;
      *(float4*)(orow + c0) = o0;
      *(float4*)(orow + c0 + 4) = o1;
    }
  }
  if (tid < 100) orow[32000 + tid] = 1e-4f;
  __syncthreads();   // drains vmem: streamed stores visible in L2 before RMW
  if (tid < 128) {
    int idx = encidx[b * 128 + tid];
    float v = expf(psic[(size_t)r * 128 + tid] - M) * iZ;
    atomicAdd(&orow[idx], v);
  }
}

// FALLBACK pass B (recompute) if workspace can't hold PSI16 -- round-1 kernel.
__global__ __launch_bounds__(256) void k_p2b(const unsigned short* __restrict__ S16,
                                             const unsigned short* __restrict__ WG16,
                                             const float* __restrict__ wgb,
                                             const float* __restrict__ MZ,
                                             const float* __restrict__ psic,
                                             const int* __restrict__ encidx,
                                             float* __restrict__ outp) {
  int nc = blockIdx.x, mt = blockIdx.y;
  int tid = threadIdx.x;
  if (nc == 250) {  // OOV columns [32000, 32100)
    for (int p = tid; p < 128 * 100; p += 256) {
      int rl = p / 100, c2 = p - rl * 100;
      int rg = mt * 128 + rl;
      outp[(size_t)rg * VT_ + 32000 + c2] = 1e-4f;
    }
    __syncthreads();
    if (tid < 128) {
      int rg = mt * 128 + tid, b = rg >> 6;
      float M = MZ[2 * rg];
      float iZ = 1.f / MZ[2 * rg + 1];
      for (int s = 0; s < 128; s++) {
        int idx = encidx[b * 128 + s];
        if (idx >= 32000) {
          float v = expf(psic[(size_t)rg * 128 + s] - M) * iZ;
          outp[(size_t)rg * VT_ + idx] += v;
        }
      }
    }
    return;
  }
  __shared__ unsigned short lA[128 * 64];
  __shared__ unsigned short lB[128 * 64];
  int wid = tid >> 6, lane = tid & 63;
  int wm = wid >> 1, wn = wid & 1;
  int quad = lane >> 4, l15 = lane & 15;
  f32x4_t acc[4][4];
#pragma unroll
  for (int i = 0; i < 4; i++)
#pragma unroll
    for (int j = 0; j < 4; j++) acc[i][j] = (f32x4_t){0.f, 0.f, 0.f, 0.f};
  for (int kt = 0; kt < 4; kt++) {
#pragma unroll
    for (int u = 0; u < 4; u++) {
      int c = u * 256 + tid;
      int row = c >> 3, ko = (c & 7) * 8;
      __builtin_amdgcn_global_load_lds(
          (const __attribute__((address_space(1))) unsigned int*)(S16 + (size_t)(mt * 128 + row) * 256 + kt * 64 + ko),
          (__attribute__((address_space(3))) unsigned int*)(lA + c * 8), 16, 0, 0);
      __builtin_amdgcn_global_load_lds(
          (const __attribute__((address_space(1))) unsigned int*)(WG16 + (size_t)(nc * 128 + row) * 256 + kt * 64 + ko),
          (__attribute__((address_space(3))) unsigned int*)(lB + c * 8), 16, 0, 0);
    }
    __syncthreads();
#pragma unroll
    for (int ks = 0; ks < 2; ks++) {
      bf16x8_t af[4], bfr[4];
#pragma unroll
      for (int i = 0; i < 4; i++) af[i] = *(const bf16x8_t*)(lA + (wm * 64 + i * 16 + l15) * 64 + ks * 32 + quad * 8);
#pragma unroll
      for (int j = 0; j < 4; j++) bfr[j] = *(const bf16x8_t*)(lB + (wn * 64 + j * 16 + l15) * 64 + ks * 32 + quad * 8);
#pragma unroll
      for (int i = 0; i < 4; i++)
#pragma unroll
        for (int j = 0; j < 4; j++)
          acc[i][j] = __builtin_amdgcn_mfma_f32_16x16x32_bf16(af[i], bfr[j], acc[i][j], 0, 0, 0);
    }
    __syncthreads();
  }
  float bj[4];
#pragma unroll
  for (int j = 0; j < 4; j++) bj[j] = wgb[nc * 128 + wn * 64 + j * 16 + l15];
#pragma unroll
  for (int i = 0; i < 4; i++) {
#pragma unroll
    for (int p = 0; p < 4; p++) {
      int rg = mt * 128 + wm * 64 + i * 16 + quad * 4 + p;
      float M = MZ[2 * rg];
      float iZ = 1.f / MZ[2 * rg + 1];
      size_t base = (size_t)rg * VT_ + nc * 128 + wn * 64 + l15;
#pragma unroll
      for (int j = 0; j < 4; j++)
        outp[base + j * 16] = expf(acc[i][j][p] + bj[j] - M) * iZ;
    }
  }
  __syncthreads();
  int nlo = nc * 128, nhi = nlo + 128;
  if (tid < 128) {
    int rg = mt * 128 + tid, b = rg >> 6;
    float M = MZ[2 * rg];
    float iZ = 1.f / MZ[2 * rg + 1];
    for (int s = 0; s < 128; s++) {
      int idx = encidx[b * 128 + s];
      if (idx >= nlo && idx < nhi) {
        float v = expf(psic[(size_t)rg * 128 + s] - M) * iZ;
        outp[(size_t)rg * VT_ + idx] += v;
      }
    }
  }
}

// ---------------------------------------------------------------- launch
extern "C" void kernel_launch(void* const* d_in, const int* in_sizes, int n_in,
                              void* d_out, int out_size, void* d_ws, size_t ws_size,
                              hipStream_t stream) {
  (void)in_sizes; (void)n_in; (void)out_size;
  const int*   inputs  = (const int*)d_in[0];
  const float* encoded = (const float*)d_in[1];
  const int*   encidx  = (const int*)d_in[2];
  const float* bridge  = (const float*)d_in[3];
  const float* embed   = (const float*)d_in[4];
  const float* wih     = (const float*)d_in[5];
  const float* whh     = (const float*)d_in[6];
  const float* bih     = (const float*)d_in[7];
  const float* bhh     = (const float*)d_in[8];
  const float* wg      = (const float*)d_in[9];
  const float* wgb     = (const float*)d_in[10];
  const float* wo      = (const float*)d_in[11];
  const float* wob     = (const float*)d_in[12];
  float* out = (float*)d_out;

  char* ws = (char*)d_ws;
  size_t off = 0;
  auto alloc = [&](size_t bytes) -> void* {
    void* p = ws + off;
    off += (bytes + 255) & ~(size_t)255;
    return p;
  };
  unsigned short* WG16  = (unsigned short*)alloc((size_t)32000 * 256 * 2);
  unsigned short* WHH16 = (unsigned short*)alloc((size_t)768 * 256 * 2);
  float* S32            = (float*)alloc((size_t)2048 * 256 * 4);
  unsigned short* S16   = (unsigned short*)alloc((size_t)2048 * 256 * 2);
  float* ENCSC          = (float*)alloc((size_t)4096 * 256 * 4);
  float* ENCIH          = (float*)alloc((size_t)4096 * 768 * 4);
  float* XG             = (float*)alloc((size_t)2048 * 768 * 4);
  float* S0             = (float*)alloc((size_t)32 * 256 * 4);
  float* PSIC           = (float*)alloc((size_t)2048 * 128 * 4);
  float* PMAX           = (float*)alloc((size_t)2048 * 256 * 4);
  float* PSUM           = (float*)alloc((size_t)2048 * 256 * 4);
  float* MZ             = (float*)alloc((size_t)2048 * 2 * 4);
  unsigned short* PSI16 = (unsigned short*)alloc((size_t)2048 * 32000 * 2);
  bool have_psi = (ws_size == 0) || (off <= ws_size);  // ws_size 0 => unknown, assume big

  k_conv<<<1024, 256, 0, stream>>>(wg, WG16, 32000 * 256 / 4);
  k_conv<<<192, 256, 0, stream>>>(whh, WHH16, 768 * 256 / 4);
  k_enc<<<dim3(64, 4), 256, 0, stream>>>(encoded, wo, wob, ENCSC);
  k_s0<<<32, 256, 0, stream>>>(encoded, bridge, S0);
  k_xg<<<dim3(32, 12), 256, 0, stream>>>(embed, inputs, wih, bih, XG);
  k_encih<<<4096, 256, 0, stream>>>(encoded, wih, encidx, inputs, ENCIH);
  k_seq<<<32, 768, 0, stream>>>(WHH16, bhh, XG, ENCSC, ENCIH, encidx, inputs, S0, S32, S16);
  k_psic<<<dim3(32, 2), 256, 0, stream>>>(S32, ENCSC, encidx, PSIC);
  if (have_psi) {
    k_p2a<true><<<dim3(250, 16), 256, 0, stream>>>(S16, WG16, wgb, PMAX, PSUM, PSI16);
    k_p2m<<<2048, 256, 0, stream>>>(PMAX, PSUM, PSIC, MZ);
    k_pb<<<2048, 256, 0, stream>>>(PSI16, MZ, PSIC, encidx, out);
  } else {
    k_p2a<false><<<dim3(250, 16), 256, 0, stream>>>(S16, WG16, wgb, PMAX, PSUM, nullptr);
    k_p2m<<<2048, 256, 0, stream>>>(PMAX, PSUM, PSIC, MZ);
    k_p2b<<<dim3(251, 16), 256, 0, stream>>>(S16, WG16, wgb, MZ, PSIC, encidx, out);
  }
}

// Round 3
// 849.703 us; speedup vs baseline: 1.4615x; 1.0755x over previous
//
#include <hip/hip_runtime.h>
#include <math.h>
#include <stdint.h>

// Problem constants
static const int VOC  = 32000;
static const int VT_  = 32100;

typedef __attribute__((ext_vector_type(8))) short bf16x8_t;
typedef __attribute__((ext_vector_type(4))) float f32x4_t;

__device__ __forceinline__ unsigned short f2bf(float f) {
  union { float f; unsigned int u; } v; v.f = f;
  unsigned int u = v.u;
  u = u + 0x7FFFu + ((u >> 16) & 1u);   // RNE
  return (unsigned short)(u >> 16);
}
__device__ __forceinline__ float bf2f(unsigned short u) {
  union { unsigned int i; float f; } w; w.i = ((unsigned int)u) << 16; return w.f;
}
__device__ __forceinline__ float bfbits(unsigned int u) {
  union { unsigned int i; float f; } w; w.i = u; return w.f;
}
// position of the j-th set bit (ascending) across the 128-bit mask (m0,m1)
__device__ __forceinline__ int nth_set(unsigned long long m0, unsigned long long m1, int j) {
  int c0 = __popcll(m0);
  unsigned long long m = m0; int base = 0;
  if (j >= c0) { j -= c0; m = m1; base = 64; }
  for (int k = 0; k < j; k++) m &= m - 1;
  return base + (__ffsll((long long)m) - 1);
}

// ---------------------------------------------------------------- utilities
__global__ void k_conv(const float* __restrict__ src, unsigned short* __restrict__ dst, int n4) {
  int i = blockIdx.x * blockDim.x + threadIdx.x;
  int stride = gridDim.x * blockDim.x;
  for (; i < n4; i += stride) {
    float4 f = ((const float4*)src)[i];
    ushort4 o;
    o.x = f2bf(f.x); o.y = f2bf(f.y); o.z = f2bf(f.z); o.w = f2bf(f.w);
    ((ushort4*)dst)[i] = o;
  }
}

// enc_scores = tanh(encoded @ Wo^T + Wo_b): M=4096 (b,s), N=256, K=512
__global__ __launch_bounds__(256) void k_enc(const float* __restrict__ enc,
                                             const float* __restrict__ wo,
                                             const float* __restrict__ wob,
                                             float* __restrict__ outp) {
  int bm = blockIdx.x, bn = blockIdx.y;
  int tid = threadIdx.x;
  int ti = tid & 15, tj = tid >> 4;
  int r0 = bm * 64 + ti * 4;
  int n0 = bn * 64 + tj * 4;
  const float4* A[4]; const float4* B[4];
#pragma unroll
  for (int i = 0; i < 4; i++) A[i] = (const float4*)(enc + (size_t)(r0 + i) * 512);
#pragma unroll
  for (int j = 0; j < 4; j++) B[j] = (const float4*)(wo + (size_t)(n0 + j) * 512);
  float acc[4][4];
#pragma unroll
  for (int i = 0; i < 4; i++)
#pragma unroll
    for (int j = 0; j < 4; j++) acc[i][j] = 0.f;
  for (int k = 0; k < 128; k++) {
    float4 a[4], b[4];
#pragma unroll
    for (int i = 0; i < 4; i++) a[i] = A[i][k];
#pragma unroll
    for (int j = 0; j < 4; j++) b[j] = B[j][k];
#pragma unroll
    for (int i = 0; i < 4; i++)
#pragma unroll
      for (int j = 0; j < 4; j++)
        acc[i][j] += a[i].x * b[j].x + a[i].y * b[j].y + a[i].z * b[j].z + a[i].w * b[j].w;
  }
#pragma unroll
  for (int i = 0; i < 4; i++)
#pragma unroll
    for (int j = 0; j < 4; j++)
      outp[(size_t)(r0 + i) * 256 + n0 + j] = tanhf(acc[i][j] + wob[n0 + j]);
}

// Xg = embed[inputs] @ Wih[:, :256]^T + b_ih: M=2048, N=768, K=256
__global__ __launch_bounds__(256) void k_xg(const float* __restrict__ embed,
                                            const int* __restrict__ inputs,
                                            const float* __restrict__ wih,
                                            const float* __restrict__ bih,
                                            float* __restrict__ xg) {
  int bm = blockIdx.x, bn = blockIdx.y;
  int tid = threadIdx.x;
  int ti = tid & 15, tj = tid >> 4;
  int r0 = bm * 64 + ti * 4;
  int n0 = bn * 64 + tj * 4;
  const float4* A[4]; const float4* B[4];
#pragma unroll
  for (int i = 0; i < 4; i++) A[i] = (const float4*)(embed + (size_t)inputs[r0 + i] * 256);
#pragma unroll
  for (int j = 0; j < 4; j++) B[j] = (const float4*)(wih + (size_t)(n0 + j) * 768);
  float acc[4][4];
#pragma unroll
  for (int i = 0; i < 4; i++)
#pragma unroll
    for (int j = 0; j < 4; j++) acc[i][j] = 0.f;
  for (int k = 0; k < 64; k++) {
    float4 a[4], b[4];
#pragma unroll
    for (int i = 0; i < 4; i++) a[i] = A[i][k];
#pragma unroll
    for (int j = 0; j < 4; j++) b[j] = B[j][k];
#pragma unroll
    for (int i = 0; i < 4; i++)
#pragma unroll
      for (int j = 0; j < 4; j++)
        acc[i][j] += a[i].x * b[j].x + a[i].y * b[j].y + a[i].z * b[j].z + a[i].w * b[j].w;
  }
#pragma unroll
  for (int i = 0; i < 4; i++)
#pragma unroll
    for (int j = 0; j < 4; j++)
      xg[(size_t)(r0 + i) * 768 + n0 + j] = acc[i][j] + bih[n0 + j];
}

// s0 = encoded[:, -1, :] @ bridge^T
__global__ __launch_bounds__(256) void k_s0(const float* __restrict__ enc,
                                            const float* __restrict__ bw,
                                            float* __restrict__ s0) {
  int b = blockIdx.x, h = threadIdx.x;
  const float4* a4 = (const float4*)(enc + ((size_t)b * 128 + 127) * 512);
  const float4* w4 = (const float4*)(bw + (size_t)h * 512);
  float acc = 0.f;
  for (int k = 0; k < 128; k++) {
    float4 a = a4[k], w = w4[k];
    acc += a.x * w.x + a.y * w.y + a.z * w.z + a.w * w.w;
  }
  s0[b * 256 + h] = acc;
}

// ENC_ih[b,s,:] = encoded[b,s,:] @ Wih[:, 256:768]^T  -- only where token ever matches
__global__ __launch_bounds__(256) void k_encih(const float* __restrict__ enc,
                                               const float* __restrict__ wih,
                                               const int* __restrict__ encidx,
                                               const int* __restrict__ inputs,
                                               float* __restrict__ encih) {
  __shared__ int flag;
  int bs = blockIdx.x;
  int b = bs >> 7;
  int tid = threadIdx.x;
  int idx = encidx[bs];
  if (tid < 64) {
    unsigned long long m = __ballot(inputs[b * 64 + tid] == idx);
    if (tid == 0) flag = (m != 0ULL);
  }
  __syncthreads();
  if (!flag) return;
  const float4* e4 = (const float4*)(enc + (size_t)bs * 512);
  for (int d = tid; d < 768; d += 256) {
    const float4* w4 = (const float4*)(wih + (size_t)d * 768 + 256);
    float acc = 0.f;
    for (int k = 0; k < 128; k++) {
      float4 e = e4[k], w = w4[k];
      acc += e.x * w.x + e.y * w.y + e.z * w.z + e.w * w.w;
    }
    encih[(size_t)bs * 768 + d] = acc;
  }
}

// -------------------------------------------------------- sequential GRU
// One block per batch row b: 768 threads = 12 waves.
// Weight residency: k in [0,160) in VGPRs (20 bf16x8 frags = 80 VGPR/lane,
// ~140 total < 170 cap at 12 waves/CU -> no spill); k in [160,256) in LDS
// (144 KB, per-wave 1KB tiles laid out so each lane reads its own contiguous
// 16B -> conflict-free). Common-path barriers reduced to 2/step: match
// positions precomputed as 128-bit masks (ballot prologue), xg row
// prefetched into registers before the MFMA phase.
__global__ __launch_bounds__(768, 1) void k_seq(
    const unsigned short* __restrict__ whb,  // [768][256] bf16 W_hh
    const float* __restrict__ bhh,
    const float* __restrict__ xg, const float* __restrict__ encsc,
    const float* __restrict__ encih, const int* __restrict__ encidx,
    const int* __restrict__ inputs, const float* __restrict__ s0,
    float* __restrict__ S32, unsigned short* __restrict__ S16) {
  __shared__ float sbuf[256];
  __shared__ __align__(16) unsigned short sb16[256];
  __shared__ float ghp[768];
  __shared__ float psis[128];
  __shared__ int eidx_sh[128];
  __shared__ int inp_sh[64];
  __shared__ unsigned long long mmask[64][2];
  __shared__ __align__(16) unsigned short wlds[73728];  // 144 KB: [wid][c][kt2][(l15*4+quad)*8]
  int b = blockIdx.x;
  int tid = threadIdx.x;
  int wid = tid >> 6, lane = tid & 63;
  int quad = lane >> 4, l15 = lane & 15;
  int n0 = wid * 64;                 // this wave's 64 output columns
  int h = tid;                       // gate thread id (tid<256)
  // --- stage k in [160,256) into LDS (each thread writes its own 12 granules)
#pragma unroll
  for (int c = 0; c < 4; c++)
#pragma unroll
    for (int kt2 = 0; kt2 < 3; kt2++) {
      int4 v = *(const int4*)(whb + (size_t)(n0 + c * 16 + l15) * 256 + 160 + kt2 * 32 + quad * 8);
      *(int4*)(wlds + wid * 6144 + (c * 3 + kt2) * 512 + (l15 * 4 + quad) * 8) = v;
    }
  // --- preload k in [0,160) into VGPRs
  bf16x8_t wf[20];
#pragma unroll
  for (int c = 0; c < 4; c++)
#pragma unroll
    for (int kt = 0; kt < 5; kt++)
      wf[c * 5 + kt] = *(const bf16x8_t*)(whb + (size_t)(n0 + c * 16 + l15) * 256 + kt * 32 + quad * 8);
  float bR = 0.f, bZ = 0.f, bN = 0.f, ctxR = 0.f, ctxZ = 0.f, ctxN = 0.f;
  if (tid < 256) {
    bR = bhh[h]; bZ = bhh[256 + h]; bN = bhh[512 + h];
    float v = s0[b * 256 + tid];
    sbuf[tid] = v;
    sb16[tid] = f2bf(v);
  }
  if (tid < 128) eidx_sh[tid] = encidx[b * 128 + tid];
  if (tid < 64) inp_sh[tid] = inputs[b * 64 + tid];
  __syncthreads();
  // --- precompute per-step match masks (waves 0,1 cover s=0..127)
  if (tid < 128) {
    int e = eidx_sh[tid];
    for (int t = 0; t < 64; t++) {
      unsigned long long bal = __ballot(e == inp_sh[t]);
      if (lane == 0) mmask[t][wid] = bal;
    }
  }
  __syncthreads();
  for (int t = 0; t < 64; t++) {
    int r = b * 64 + t;
    // prefetch xg row (independent of everything this step; lands under MFMA+B1)
    float xr0 = 0.f, xr1 = 0.f, xr2 = 0.f;
    if (tid < 256) {
      const float* xr = xg + (size_t)r * 768;
      xr0 = xr[h]; xr1 = xr[256 + h]; xr2 = xr[512 + h];
    }
    // --- gh = s @ W_hh^T via MFMA (A = broadcast s-row; C row0 = s@W^T)
    f32x4_t a0 = {0.f,0.f,0.f,0.f}, a1 = {0.f,0.f,0.f,0.f};
    f32x4_t a2 = {0.f,0.f,0.f,0.f}, a3 = {0.f,0.f,0.f,0.f};
#pragma unroll
    for (int kt = 0; kt < 5; kt++) {
      bf16x8_t af = *(const bf16x8_t*)(sb16 + kt * 32 + quad * 8);
      a0 = __builtin_amdgcn_mfma_f32_16x16x32_bf16(af, wf[ 0 + kt], a0, 0, 0, 0);
      a1 = __builtin_amdgcn_mfma_f32_16x16x32_bf16(af, wf[ 5 + kt], a1, 0, 0, 0);
      a2 = __builtin_amdgcn_mfma_f32_16x16x32_bf16(af, wf[10 + kt], a2, 0, 0, 0);
      a3 = __builtin_amdgcn_mfma_f32_16x16x32_bf16(af, wf[15 + kt], a3, 0, 0, 0);
    }
#pragma unroll
    for (int kt2 = 0; kt2 < 3; kt2++) {
      bf16x8_t af = *(const bf16x8_t*)(sb16 + (5 + kt2) * 32 + quad * 8);
      const unsigned short* wb = wlds + wid * 6144 + kt2 * 512 + (l15 * 4 + quad) * 8;
      a0 = __builtin_amdgcn_mfma_f32_16x16x32_bf16(af, *(const bf16x8_t*)(wb +    0), a0, 0, 0, 0);
      a1 = __builtin_amdgcn_mfma_f32_16x16x32_bf16(af, *(const bf16x8_t*)(wb + 1536), a1, 0, 0, 0);
      a2 = __builtin_amdgcn_mfma_f32_16x16x32_bf16(af, *(const bf16x8_t*)(wb + 3072), a2, 0, 0, 0);
      a3 = __builtin_amdgcn_mfma_f32_16x16x32_bf16(af, *(const bf16x8_t*)(wb + 4608), a3, 0, 0, 0);
    }
    if (lane < 16) {
      ghp[n0 +      lane] = a0[0];
      ghp[n0 + 16 + lane] = a1[0];
      ghp[n0 + 32 + lane] = a2[0];
      ghp[n0 + 48 + lane] = a3[0];
    }
    __syncthreads();                                   // B1: gh complete
    if (tid < 256) {
      float hr = ghp[h] + bR;
      float hz = ghp[256 + h] + bZ;
      float hn = ghp[512 + h] + bN;
      float gr = xr0 + ctxR;
      float gz = xr1 + ctxZ;
      float gn = xr2 + ctxN;
      float rgate = 1.f / (1.f + expf(-(gr + hr)));
      float zgate = 1.f / (1.f + expf(-(gz + hz)));
      float ngate = tanhf(gn + rgate * hn);
      float sold = sbuf[h];
      float snew = (1.f - zgate) * ngate + zgate * sold;
      unsigned short u16 = f2bf(snew);
      S32[(size_t)r * 256 + h] = snew;
      S16[(size_t)r * 256 + h] = u16;
      sbuf[h] = snew;                                  // own-element RMW, safe
      sb16[h] = u16;
    }
    __syncthreads();                                   // B2: s_t complete
    if (t == 63) break;
    // --- matched-position copy-attention for ctx(t) -> used at step t+1
    unsigned long long m0 = mmask[t][0], m1 = mmask[t][1];
    int mc = __popcll(m0) + __popcll(m1);
    if (mc > 0) {                                      // uniform branch
      for (int j = wid; j < mc; j += 12) {
        int s = nth_set(m0, m1, j);
        const float4* e4 = (const float4*)(encsc + (size_t)(b * 128 + s) * 256);
        float4 ev = e4[lane];
        float4 sv = ((const float4*)sbuf)[lane];
        float v = ev.x * sv.x + ev.y * sv.y + ev.z * sv.z + ev.w * sv.w;
#pragma unroll
        for (int off = 32; off >= 1; off >>= 1) v += __shfl_down(v, off);
        if (lane == 0) psis[j] = v + (eidx_sh[s] == 0 ? -1000.f : 0.f);
      }
      __syncthreads();                                 // B4
      if (tid == 0) {
        float mx = -3e38f;
        for (int j = 0; j < mc; j++) mx = fmaxf(mx, psis[j]);
        if (mx < -500.f) {       // all matches are pads -> reference cw == 0
          for (int j = 0; j < mc; j++) psis[j] = 0.f;
        } else {
          float ss = 0.f;
          for (int j = 0; j < mc; j++) { float e = expf(psis[j] - mx); psis[j] = e; ss += e; }
          float rs = 1.f / ss;
          for (int j = 0; j < mc; j++) psis[j] *= rs;
        }
      }
      __syncthreads();                                 // B5
      if (tid < 256) {
        ctxR = 0.f; ctxZ = 0.f; ctxN = 0.f;
        unsigned long long mm0 = m0, mm1 = m1;
        for (int j = 0; j < mc; j++) {
          int s;
          if (mm0) { s = __ffsll((long long)mm0) - 1; mm0 &= mm0 - 1; }
          else     { s = 64 + __ffsll((long long)mm1) - 1; mm1 &= mm1 - 1; }
          float c = psis[j];
          const float* e = encih + (size_t)(b * 128 + s) * 768;
          ctxR += c * e[h]; ctxZ += c * e[256 + h]; ctxN += c * e[512 + h];
        }
      }
    } else if (tid < 256) {
      ctxR = 0.f; ctxZ = 0.f; ctxN = 0.f;
    }
  }
}

// psic = S32 x ENCSC^T (batched, block-diagonal) + pad mask. grid (32 b, 2 ny)
__global__ __launch_bounds__(256) void k_psic(const float* __restrict__ S32,
                                              const float* __restrict__ encsc,
                                              const int* __restrict__ encidx,
                                              float* __restrict__ psic) {
  int b = blockIdx.x, ny = blockIdx.y;
  int tid = threadIdx.x;
  int ti = tid & 15, tj = tid >> 4;
  int r0 = b * 64 + ti * 4;      // global (b,t) row
  int s0 = ny * 64 + tj * 4;
  const float4* A[4]; const float4* B[4];
#pragma unroll
  for (int i = 0; i < 4; i++) A[i] = (const float4*)(S32 + (size_t)(r0 + i) * 256);
#pragma unroll
  for (int j = 0; j < 4; j++) B[j] = (const float4*)(encsc + (size_t)(b * 128 + s0 + j) * 256);
  float acc[4][4];
#pragma unroll
  for (int i = 0; i < 4; i++)
#pragma unroll
    for (int j = 0; j < 4; j++) acc[i][j] = 0.f;
  for (int k = 0; k < 64; k++) {
    float4 a[4], bb[4];
#pragma unroll
    for (int i = 0; i < 4; i++) a[i] = A[i][k];
#pragma unroll
    for (int j = 0; j < 4; j++) bb[j] = B[j][k];
#pragma unroll
    for (int i = 0; i < 4; i++)
#pragma unroll
      for (int j = 0; j < 4; j++)
        acc[i][j] += a[i].x * bb[j].x + a[i].y * bb[j].y + a[i].z * bb[j].z + a[i].w * bb[j].w;
  }
#pragma unroll
  for (int i = 0; i < 4; i++)
#pragma unroll
    for (int j = 0; j < 4; j++) {
      float v = acc[i][j] + (encidx[b * 128 + s0 + j] == 0 ? -1000.f : 0.f);
      psic[(size_t)(r0 + i) * 128 + s0 + j] = v;
    }
}

// psi_g: 128x128 bf16 MFMA tile, 2-phase prefetch pipeline, writes bf16 psi.
// No reduction epilogue -- k_pb computes M,Z per row from the rounded values.
__global__ __launch_bounds__(256, 2) void k_p2a(const unsigned short* __restrict__ S16,
                                                const unsigned short* __restrict__ WG16,
                                                const float* __restrict__ wgb,
                                                unsigned short* __restrict__ psi16) {
  __shared__ unsigned short lA[2][128 * 64];
  __shared__ unsigned short lB[2][128 * 64];
  int nc = blockIdx.x, mt = blockIdx.y;
  int tid = threadIdx.x;
  int wid = tid >> 6, lane = tid & 63;
  int wm = wid >> 1, wn = wid & 1;
  int quad = lane >> 4, l15 = lane & 15;
  f32x4_t acc[4][4];
#pragma unroll
  for (int i = 0; i < 4; i++)
#pragma unroll
    for (int j = 0; j < 4; j++) acc[i][j] = (f32x4_t){0.f, 0.f, 0.f, 0.f};

#define STAGE_P2A(buf, kt) do {                                                            \
    _Pragma("unroll")                                                                      \
    for (int u = 0; u < 4; u++) {                                                          \
      int c = u * 256 + tid;                                                               \
      int row = c >> 3;                                                                    \
      int ko = ((c & 7) ^ (row & 7)) * 8;                                                  \
      __builtin_amdgcn_global_load_lds(                                                    \
          (const __attribute__((address_space(1))) unsigned int*)(S16 + (size_t)(mt * 128 + row) * 256 + (kt) * 64 + ko), \
          (__attribute__((address_space(3))) unsigned int*)(&lA[buf][c * 8]), 16, 0, 0);   \
      __builtin_amdgcn_global_load_lds(                                                    \
          (const __attribute__((address_space(1))) unsigned int*)(WG16 + (size_t)(nc * 128 + row) * 256 + (kt) * 64 + ko), \
          (__attribute__((address_space(3))) unsigned int*)(&lB[buf][c * 8]), 16, 0, 0);   \
    }                                                                                      \
  } while (0)

  STAGE_P2A(0, 0);
  __syncthreads();
  for (int kt = 0; kt < 4; kt++) {
    int cur = kt & 1;
    if (kt < 3) STAGE_P2A(cur ^ 1, kt + 1);   // overlap next stage with compute
#pragma unroll
    for (int ks = 0; ks < 2; ks++) {
      bf16x8_t af[4], bfr[4];
      int slot = ((ks * 4 + quad) ^ (l15 & 7)) * 8;
#pragma unroll
      for (int i = 0; i < 4; i++) af[i] = *(const bf16x8_t*)(&lA[cur][(wm * 64 + i * 16 + l15) * 64 + slot]);
#pragma unroll
      for (int j = 0; j < 4; j++) bfr[j] = *(const bf16x8_t*)(&lB[cur][(wn * 64 + j * 16 + l15) * 64 + slot]);
#pragma unroll
      for (int i = 0; i < 4; i++)
#pragma unroll
        for (int j = 0; j < 4; j++)
          acc[i][j] = __builtin_amdgcn_mfma_f32_16x16x32_bf16(af[i], bfr[j], acc[i][j], 0, 0, 0);
    }
    __syncthreads();   // drains vmem (stage kt+1) + protects buffer reuse
  }
#undef STAGE_P2A
  float bj[4];
#pragma unroll
  for (int j = 0; j < 4; j++) bj[j] = wgb[nc * 128 + wn * 64 + j * 16 + l15];
#pragma unroll
  for (int i = 0; i < 4; i++) {
#pragma unroll
    for (int p = 0; p < 4; p++) {
      int rg = mt * 128 + wm * 64 + i * 16 + quad * 4 + p;
      size_t base = (size_t)rg * 32000 + nc * 128 + wn * 64 + l15;
#pragma unroll
      for (int j = 0; j < 4; j++)
        psi16[base + j * 16] = f2bf(acc[i][j][p] + bj[j]);
    }
  }
}

// pass B: stage bf16 psi row in LDS, compute M,Z in-block, stream p = exp/Z,
// OOV fill + copy scatter. One block per output row.
__global__ __launch_bounds__(256) void k_pb(const unsigned short* __restrict__ psi16,
                                            const float* __restrict__ psic,
                                            const int* __restrict__ encidx,
                                            float* __restrict__ outp) {
  __shared__ __align__(16) unsigned short lp[32000];
  __shared__ float lc[128];
  __shared__ float rtmp[8];
  __shared__ float MZsh[2];
  int r = blockIdx.x;          // 0..2047
  int b = r >> 6;
  int tid = threadIdx.x;
  const unsigned short* prow = psi16 + (size_t)r * 32000;
  float* orow = outp + (size_t)r * VT_;
#pragma unroll
  for (int u = 0; u < 16; u++) {
    int c = u * 256 + tid;
    if (c < 4000)
      __builtin_amdgcn_global_load_lds(
          (const __attribute__((address_space(1))) unsigned int*)(prow + c * 8),
          (__attribute__((address_space(3))) unsigned int*)(lp + c * 8), 16, 0, 0);
  }
  if (tid < 128) lc[tid] = psic[(size_t)r * 128 + tid];
  __syncthreads();
  // row max
  float m = -3e38f;
  for (int c = tid; c < 32000; c += 256) m = fmaxf(m, bf2f(lp[c]));
  if (tid < 128) m = fmaxf(m, lc[tid]);
#pragma unroll
  for (int off = 32; off >= 1; off >>= 1) m = fmaxf(m, __shfl_xor(m, off));
  if ((tid & 63) == 0) rtmp[tid >> 6] = m;
  __syncthreads();
  if (tid == 0) MZsh[0] = fmaxf(fmaxf(rtmp[0], rtmp[1]), fmaxf(rtmp[2], rtmp[3]));
  __syncthreads();
  float M = MZsh[0];
  // row sum
  float z = 0.f;
  for (int c = tid; c < 32000; c += 256) z += expf(bf2f(lp[c]) - M);
  if (tid < 128) z += expf(lc[tid] - M);
#pragma unroll
  for (int off = 32; off >= 1; off >>= 1) z += __shfl_xor(z, off);
  if ((tid & 63) == 0) rtmp[4 + (tid >> 6)] = z;
  __syncthreads();
  if (tid == 0) MZsh[1] = rtmp[4] + rtmp[5] + rtmp[6] + rtmp[7];
  __syncthreads();
  float iZ = 1.f / MZsh[1];
  // stream out
#pragma unroll 2
  for (int u = 0; u < 16; u++) {
    int c8 = u * 256 + tid;
    if (c8 < 4000) {
      int c0 = c8 * 8;
      int4 v = *(const int4*)(lp + c0);
      float4 o0, o1;
      unsigned int x;
      x = (unsigned int)v.x;
      o0.x = expf(bfbits(x << 16) - M) * iZ;
      o0.y = expf(bfbits(x & 0xffff0000u) - M) * iZ;
      x = (unsigned int)v.y;
      o0.z = expf(bfbits(x << 16) - M) * iZ;
      o0.w = expf(bfbits(x & 0xffff0000u) - M) * iZ;
      x = (unsigned int)v.z;
      o1.x = expf(bfbits(x << 16) - M) * iZ;
      o1.y = expf(bfbits(x & 0xffff0000u) - M) * iZ;
      x = (unsigned int)v.w;
      o1.z = expf(bfbits(x << 16) - M) * iZ;
      o1.w = expf(bfbits(x & 0xffff0000u) - M) * iZ;
      *(float4*)(orow + c0) = o0;
      *(float4*)(orow + c0 + 4) = o1;
    }
  }
  if (tid < 100) orow[32000 + tid] = 1e-4f;
  __syncthreads();   // drains vmem: streamed stores visible in L2 before RMW
  if (tid < 128) {
    int idx = encidx[b * 128 + tid];
    float v = expf(lc[tid] - M) * iZ;
    atomicAdd(&orow[idx], v);
  }
}

// ---------------------------------------------------------------- launch
extern "C" void kernel_launch(void* const* d_in, const int* in_sizes, int n_in,
                              void* d_out, int out_size, void* d_ws, size_t ws_size,
                              hipStream_t stream) {
  (void)in_sizes; (void)n_in; (void)out_size; (void)ws_size;
  const int*   inputs  = (const int*)d_in[0];
  const float* encoded = (const float*)d_in[1];
  const int*   encidx  = (const int*)d_in[2];
  const float* bridge  = (const float*)d_in[3];
  const float* embed   = (const float*)d_in[4];
  const float* wih     = (const float*)d_in[5];
  const float* whh     = (const float*)d_in[6];
  const float* bih     = (const float*)d_in[7];
  const float* bhh     = (const float*)d_in[8];
  const float* wg      = (const float*)d_in[9];
  const float* wgb     = (const float*)d_in[10];
  const float* wo      = (const float*)d_in[11];
  const float* wob     = (const float*)d_in[12];
  float* out = (float*)d_out;

  char* ws = (char*)d_ws;
  size_t off = 0;
  auto alloc = [&](size_t bytes) -> void* {
    void* p = ws + off;
    off += (bytes + 255) & ~(size_t)255;
    return p;
  };
  unsigned short* WG16  = (unsigned short*)alloc((size_t)32000 * 256 * 2);
  unsigned short* WHH16 = (unsigned short*)alloc((size_t)768 * 256 * 2);
  float* S32            = (float*)alloc((size_t)2048 * 256 * 4);
  unsigned short* S16   = (unsigned short*)alloc((size_t)2048 * 256 * 2);
  float* ENCSC          = (float*)alloc((size_t)4096 * 256 * 4);
  float* ENCIH          = (float*)alloc((size_t)4096 * 768 * 4);
  float* XG             = (float*)alloc((size_t)2048 * 768 * 4);
  float* S0             = (float*)alloc((size_t)32 * 256 * 4);
  float* PSIC           = (float*)alloc((size_t)2048 * 128 * 4);
  unsigned short* PSI16 = (unsigned short*)alloc((size_t)2048 * 32000 * 2);

  k_conv<<<1024, 256, 0, stream>>>(wg, WG16, 32000 * 256 / 4);
  k_conv<<<192, 256, 0, stream>>>(whh, WHH16, 768 * 256 / 4);
  k_enc<<<dim3(64, 4), 256, 0, stream>>>(encoded, wo, wob, ENCSC);
  k_s0<<<32, 256, 0, stream>>>(encoded, bridge, S0);
  k_xg<<<dim3(32, 12), 256, 0, stream>>>(embed, inputs, wih, bih, XG);
  k_encih<<<4096, 256, 0, stream>>>(encoded, wih, encidx, inputs, ENCIH);
  k_seq<<<32, 768, 0, stream>>>(WHH16, bhh, XG, ENCSC, ENCIH, encidx, inputs, S0, S32, S16);
  k_psic<<<dim3(32, 2), 256, 0, stream>>>(S32, ENCSC, encidx, PSIC);
  k_p2a<<<dim3(250, 16), 256, 0, stream>>>(S16, WG16, wgb, PSI16);
  k_pb<<<2048, 256, 0, stream>>>(PSI16, PSIC, encidx, out);
}

// Round 4
// 837.046 us; speedup vs baseline: 1.4836x; 1.0151x over previous
//
#include <hip/hip_runtime.h>
#include <math.h>
#include <stdint.h>

// Problem constants
static const int VOC  = 32000;
static const int VT_  = 32100;

typedef __attribute__((ext_vector_type(8))) short bf16x8_t;
typedef __attribute__((ext_vector_type(4))) float f32x4_t;

__device__ __forceinline__ unsigned short f2bf(float f) {
  union { float f; unsigned int u; } v; v.f = f;
  unsigned int u = v.u;
  u = u + 0x7FFFu + ((u >> 16) & 1u);   // RNE
  return (unsigned short)(u >> 16);
}
__device__ __forceinline__ float bf2f(unsigned short u) {
  union { unsigned int i; float f; } w; w.i = ((unsigned int)u) << 16; return w.f;
}
__device__ __forceinline__ float bfbits(unsigned int u) {
  union { unsigned int i; float f; } w; w.i = u; return w.f;
}
// position of the j-th set bit (ascending) across the 128-bit mask (m0,m1)
__device__ __forceinline__ int nth_set(unsigned long long m0, unsigned long long m1, int j) {
  int c0 = __popcll(m0);
  unsigned long long m = m0; int base = 0;
  if (j >= c0) { j -= c0; m = m1; base = 64; }
  for (int k = 0; k < j; k++) m &= m - 1;
  return base + (__ffsll((long long)m) - 1);
}

// ---------------------------------------------------------------- fused preprocessing
// One launch, grid-partitioned (heavy branches first for dispatch-order balance):
//   [0,256)      k_enc   : ENCSC = tanh(encoded @ Wo^T + b)   (bm=q>>2, bn=q&3)
//   [256,640)    k_xg    : XG = embed[inputs] @ Wih[:, :256]^T + b_ih
//   [640,1664)   conv WG -> bf16
//   [1664,1676)  conv WHH -> bf16
//   [1676,1708)  k_s0    : s0 = encoded[:,-1,:] @ bridge^T
//   [1708,5804)  k_encih : ENC_ih rows (flag-gated, mostly early-exit)
__global__ __launch_bounds__(256) void k_pre(
    const float* __restrict__ wg, unsigned short* __restrict__ WG16,
    const float* __restrict__ whh, unsigned short* __restrict__ WHH16,
    const float* __restrict__ enc, const float* __restrict__ wo,
    const float* __restrict__ wob, float* __restrict__ ENCSC,
    const float* __restrict__ bridge, float* __restrict__ S0,
    const float* __restrict__ embed, const int* __restrict__ inputs,
    const float* __restrict__ wih, const float* __restrict__ bih, float* __restrict__ XG,
    const int* __restrict__ encidx, float* __restrict__ ENCIH) {
  __shared__ int flag;
  int q = blockIdx.x;
  int tid = threadIdx.x;
  if (q < 256) {
    // ---- k_enc: M=4096, N=256, K=512
    int bm = q >> 2, bn = q & 3;
    int ti = tid & 15, tj = tid >> 4;
    int r0 = bm * 64 + ti * 4;
    int n0 = bn * 64 + tj * 4;
    const float4* A[4]; const float4* B[4];
#pragma unroll
    for (int i = 0; i < 4; i++) A[i] = (const float4*)(enc + (size_t)(r0 + i) * 512);
#pragma unroll
    for (int j = 0; j < 4; j++) B[j] = (const float4*)(wo + (size_t)(n0 + j) * 512);
    float acc[4][4];
#pragma unroll
    for (int i = 0; i < 4; i++)
#pragma unroll
      for (int j = 0; j < 4; j++) acc[i][j] = 0.f;
    for (int k = 0; k < 128; k++) {
      float4 a[4], b[4];
#pragma unroll
      for (int i = 0; i < 4; i++) a[i] = A[i][k];
#pragma unroll
      for (int j = 0; j < 4; j++) b[j] = B[j][k];
#pragma unroll
      for (int i = 0; i < 4; i++)
#pragma unroll
        for (int j = 0; j < 4; j++)
          acc[i][j] += a[i].x * b[j].x + a[i].y * b[j].y + a[i].z * b[j].z + a[i].w * b[j].w;
    }
#pragma unroll
    for (int i = 0; i < 4; i++)
#pragma unroll
      for (int j = 0; j < 4; j++)
        ENCSC[(size_t)(r0 + i) * 256 + n0 + j] = tanhf(acc[i][j] + wob[n0 + j]);
  } else if (q < 640) {
    // ---- k_xg: M=2048, N=768, K=256
    int p = q - 256;
    int bm = p & 31, bn = p >> 5;
    int ti = tid & 15, tj = tid >> 4;
    int r0 = bm * 64 + ti * 4;
    int n0 = bn * 64 + tj * 4;
    const float4* A[4]; const float4* B[4];
#pragma unroll
    for (int i = 0; i < 4; i++) A[i] = (const float4*)(embed + (size_t)inputs[r0 + i] * 256);
#pragma unroll
    for (int j = 0; j < 4; j++) B[j] = (const float4*)(wih + (size_t)(n0 + j) * 768);
    float acc[4][4];
#pragma unroll
    for (int i = 0; i < 4; i++)
#pragma unroll
      for (int j = 0; j < 4; j++) acc[i][j] = 0.f;
    for (int k = 0; k < 64; k++) {
      float4 a[4], b[4];
#pragma unroll
      for (int i = 0; i < 4; i++) a[i] = A[i][k];
#pragma unroll
      for (int j = 0; j < 4; j++) b[j] = B[j][k];
#pragma unroll
      for (int i = 0; i < 4; i++)
#pragma unroll
        for (int j = 0; j < 4; j++)
          acc[i][j] += a[i].x * b[j].x + a[i].y * b[j].y + a[i].z * b[j].z + a[i].w * b[j].w;
    }
#pragma unroll
    for (int i = 0; i < 4; i++)
#pragma unroll
      for (int j = 0; j < 4; j++)
        XG[(size_t)(r0 + i) * 768 + n0 + j] = acc[i][j] + bih[n0 + j];
  } else if (q < 1664) {
    // ---- conv wg -> WG16
    int n4 = 32000 * 256 / 4;
    for (int i = (q - 640) * 256 + tid; i < n4; i += 1024 * 256) {
      float4 f = ((const float4*)wg)[i];
      ushort4 o;
      o.x = f2bf(f.x); o.y = f2bf(f.y); o.z = f2bf(f.z); o.w = f2bf(f.w);
      ((ushort4*)WG16)[i] = o;
    }
  } else if (q < 1676) {
    // ---- conv whh -> WHH16
    int n4 = 768 * 256 / 4;
    for (int i = (q - 1664) * 256 + tid; i < n4; i += 12 * 256) {
      float4 f = ((const float4*)whh)[i];
      ushort4 o;
      o.x = f2bf(f.x); o.y = f2bf(f.y); o.z = f2bf(f.z); o.w = f2bf(f.w);
      ((ushort4*)WHH16)[i] = o;
    }
  } else if (q < 1708) {
    // ---- s0
    int b = q - 1676, h = tid;
    const float4* a4 = (const float4*)(enc + ((size_t)b * 128 + 127) * 512);
    const float4* w4 = (const float4*)(bridge + (size_t)h * 512);
    float acc = 0.f;
    for (int k = 0; k < 128; k++) {
      float4 a = a4[k], w = w4[k];
      acc += a.x * w.x + a.y * w.y + a.z * w.z + a.w * w.w;
    }
    S0[b * 256 + h] = acc;
  } else {
    // ---- encih (flag-gated)
    int bs = q - 1708;
    int b = bs >> 7;
    int idx = encidx[bs];
    if (tid < 64) {
      unsigned long long m = __ballot(inputs[b * 64 + tid] == idx);
      if (tid == 0) flag = (m != 0ULL);
    }
    __syncthreads();
    if (!flag) return;
    const float4* e4 = (const float4*)(enc + (size_t)bs * 512);
    for (int d = tid; d < 768; d += 256) {
      const float4* w4 = (const float4*)(wih + (size_t)d * 768 + 256);
      float acc = 0.f;
      for (int k = 0; k < 128; k++) {
        float4 e = e4[k], w = w4[k];
        acc += e.x * w.x + e.y * w.y + e.z * w.z + e.w * w.w;
      }
      ENCIH[(size_t)bs * 768 + d] = acc;
    }
  }
}

// -------------------------------------------------------- sequential GRU
// One block per batch row b: 768 threads = 12 waves.
// Weight residency: k in [0,160) in VGPRs (20 bf16x8 frags); k in [160,256)
// in LDS (144 KB, per-wave 1KB conflict-free tiles). 2 barriers/step common
// path; match masks precomputed; xg prefetched before the MFMA phase.
__global__ __launch_bounds__(768, 1) void k_seq(
    const unsigned short* __restrict__ whb,  // [768][256] bf16 W_hh
    const float* __restrict__ bhh,
    const float* __restrict__ xg, const float* __restrict__ encsc,
    const float* __restrict__ encih, const int* __restrict__ encidx,
    const int* __restrict__ inputs, const float* __restrict__ s0,
    float* __restrict__ S32, unsigned short* __restrict__ S16) {
  __shared__ float sbuf[256];
  __shared__ __align__(16) unsigned short sb16[256];
  __shared__ float ghp[768];
  __shared__ float psis[128];
  __shared__ int eidx_sh[128];
  __shared__ int inp_sh[64];
  __shared__ unsigned long long mmask[64][2];
  __shared__ __align__(16) unsigned short wlds[73728];  // 144 KB
  int b = blockIdx.x;
  int tid = threadIdx.x;
  int wid = tid >> 6, lane = tid & 63;
  int quad = lane >> 4, l15 = lane & 15;
  int n0 = wid * 64;
  int h = tid;
#pragma unroll
  for (int c = 0; c < 4; c++)
#pragma unroll
    for (int kt2 = 0; kt2 < 3; kt2++) {
      int4 v = *(const int4*)(whb + (size_t)(n0 + c * 16 + l15) * 256 + 160 + kt2 * 32 + quad * 8);
      *(int4*)(wlds + wid * 6144 + (c * 3 + kt2) * 512 + (l15 * 4 + quad) * 8) = v;
    }
  bf16x8_t wf[20];
#pragma unroll
  for (int c = 0; c < 4; c++)
#pragma unroll
    for (int kt = 0; kt < 5; kt++)
      wf[c * 5 + kt] = *(const bf16x8_t*)(whb + (size_t)(n0 + c * 16 + l15) * 256 + kt * 32 + quad * 8);
  float bR = 0.f, bZ = 0.f, bN = 0.f, ctxR = 0.f, ctxZ = 0.f, ctxN = 0.f;
  if (tid < 256) {
    bR = bhh[h]; bZ = bhh[256 + h]; bN = bhh[512 + h];
    float v = s0[b * 256 + tid];
    sbuf[tid] = v;
    sb16[tid] = f2bf(v);
  }
  if (tid < 128) eidx_sh[tid] = encidx[b * 128 + tid];
  if (tid < 64) inp_sh[tid] = inputs[b * 64 + tid];
  __syncthreads();
  if (tid < 128) {
    int e = eidx_sh[tid];
    for (int t = 0; t < 64; t++) {
      unsigned long long bal = __ballot(e == inp_sh[t]);
      if (lane == 0) mmask[t][wid] = bal;
    }
  }
  __syncthreads();
  for (int t = 0; t < 64; t++) {
    int r = b * 64 + t;
    float xr0 = 0.f, xr1 = 0.f, xr2 = 0.f;
    if (tid < 256) {
      const float* xr = xg + (size_t)r * 768;
      xr0 = xr[h]; xr1 = xr[256 + h]; xr2 = xr[512 + h];
    }
    f32x4_t a0 = {0.f,0.f,0.f,0.f}, a1 = {0.f,0.f,0.f,0.f};
    f32x4_t a2 = {0.f,0.f,0.f,0.f}, a3 = {0.f,0.f,0.f,0.f};
#pragma unroll
    for (int kt = 0; kt < 5; kt++) {
      bf16x8_t af = *(const bf16x8_t*)(sb16 + kt * 32 + quad * 8);
      a0 = __builtin_amdgcn_mfma_f32_16x16x32_bf16(af, wf[ 0 + kt], a0, 0, 0, 0);
      a1 = __builtin_amdgcn_mfma_f32_16x16x32_bf16(af, wf[ 5 + kt], a1, 0, 0, 0);
      a2 = __builtin_amdgcn_mfma_f32_16x16x32_bf16(af, wf[10 + kt], a2, 0, 0, 0);
      a3 = __builtin_amdgcn_mfma_f32_16x16x32_bf16(af, wf[15 + kt], a3, 0, 0, 0);
    }
#pragma unroll
    for (int kt2 = 0; kt2 < 3; kt2++) {
      bf16x8_t af = *(const bf16x8_t*)(sb16 + (5 + kt2) * 32 + quad * 8);
      const unsigned short* wb = wlds + wid * 6144 + kt2 * 512 + (l15 * 4 + quad) * 8;
      a0 = __builtin_amdgcn_mfma_f32_16x16x32_bf16(af, *(const bf16x8_t*)(wb +    0), a0, 0, 0, 0);
      a1 = __builtin_amdgcn_mfma_f32_16x16x32_bf16(af, *(const bf16x8_t*)(wb + 1536), a1, 0, 0, 0);
      a2 = __builtin_amdgcn_mfma_f32_16x16x32_bf16(af, *(const bf16x8_t*)(wb + 3072), a2, 0, 0, 0);
      a3 = __builtin_amdgcn_mfma_f32_16x16x32_bf16(af, *(const bf16x8_t*)(wb + 4608), a3, 0, 0, 0);
    }
    if (lane < 16) {
      ghp[n0 +      lane] = a0[0];
      ghp[n0 + 16 + lane] = a1[0];
      ghp[n0 + 32 + lane] = a2[0];
      ghp[n0 + 48 + lane] = a3[0];
    }
    __syncthreads();                                   // B1: gh complete
    if (tid < 256) {
      float hr = ghp[h] + bR;
      float hz = ghp[256 + h] + bZ;
      float hn = ghp[512 + h] + bN;
      float gr = xr0 + ctxR;
      float gz = xr1 + ctxZ;
      float gn = xr2 + ctxN;
      float rgate = 1.f / (1.f + expf(-(gr + hr)));
      float zgate = 1.f / (1.f + expf(-(gz + hz)));
      float ngate = tanhf(gn + rgate * hn);
      float sold = sbuf[h];
      float snew = (1.f - zgate) * ngate + zgate * sold;
      unsigned short u16 = f2bf(snew);
      S32[(size_t)r * 256 + h] = snew;
      S16[(size_t)r * 256 + h] = u16;
      sbuf[h] = snew;
      sb16[h] = u16;
    }
    __syncthreads();                                   // B2: s_t complete
    if (t == 63) break;
    unsigned long long m0 = mmask[t][0], m1 = mmask[t][1];
    int mc = __popcll(m0) + __popcll(m1);
    if (mc > 0) {                                      // uniform branch
      for (int j = wid; j < mc; j += 12) {
        int s = nth_set(m0, m1, j);
        const float4* e4 = (const float4*)(encsc + (size_t)(b * 128 + s) * 256);
        float4 ev = e4[lane];
        float4 sv = ((const float4*)sbuf)[lane];
        float v = ev.x * sv.x + ev.y * sv.y + ev.z * sv.z + ev.w * sv.w;
#pragma unroll
        for (int off = 32; off >= 1; off >>= 1) v += __shfl_down(v, off);
        if (lane == 0) psis[j] = v + (eidx_sh[s] == 0 ? -1000.f : 0.f);
      }
      __syncthreads();
      if (tid == 0) {
        float mx = -3e38f;
        for (int j = 0; j < mc; j++) mx = fmaxf(mx, psis[j]);
        if (mx < -500.f) {
          for (int j = 0; j < mc; j++) psis[j] = 0.f;
        } else {
          float ss = 0.f;
          for (int j = 0; j < mc; j++) { float e = expf(psis[j] - mx); psis[j] = e; ss += e; }
          float rs = 1.f / ss;
          for (int j = 0; j < mc; j++) psis[j] *= rs;
        }
      }
      __syncthreads();
      if (tid < 256) {
        ctxR = 0.f; ctxZ = 0.f; ctxN = 0.f;
        unsigned long long mm0 = m0, mm1 = m1;
        for (int j = 0; j < mc; j++) {
          int s;
          if (mm0) { s = __ffsll((long long)mm0) - 1; mm0 &= mm0 - 1; }
          else     { s = 64 + __ffsll((long long)mm1) - 1; mm1 &= mm1 - 1; }
          float c = psis[j];
          const float* e = encih + (size_t)(b * 128 + s) * 768;
          ctxR += c * e[h]; ctxZ += c * e[256 + h]; ctxN += c * e[512 + h];
        }
      }
    } else if (tid < 256) {
      ctxR = 0.f; ctxZ = 0.f; ctxN = 0.f;
    }
  }
}

// -------------------------------------------------- fused mid: psi_g GEMM + psi_c
// blocks [0,4000): psi_g 128x128 bf16 MFMA tile, 2-phase prefetch,
//                  writes E = bf16(exp(psi)) -- psi is O(+-1) so exp is safe.
// blocks [4000,4064): psic = S32 x ENCSC^T + pad mask (fp32 precision kept).
__global__ __launch_bounds__(256, 2) void k_mid(const unsigned short* __restrict__ S16,
                                                const unsigned short* __restrict__ WG16,
                                                const float* __restrict__ wgb,
                                                unsigned short* __restrict__ pe16,
                                                const float* __restrict__ S32,
                                                const float* __restrict__ encsc,
                                                const int* __restrict__ encidx,
                                                float* __restrict__ psic) {
  __shared__ unsigned short lA[2][128 * 64];
  __shared__ unsigned short lB[2][128 * 64];
  int q = blockIdx.x;
  int tid = threadIdx.x;
  if (q >= 4000) {
    // ---- psic branch
    int q2 = q - 4000;
    int b = q2 >> 1, ny = q2 & 1;
    int ti = tid & 15, tj = tid >> 4;
    int r0 = b * 64 + ti * 4;
    int s0 = ny * 64 + tj * 4;
    const float4* A[4]; const float4* B[4];
#pragma unroll
    for (int i = 0; i < 4; i++) A[i] = (const float4*)(S32 + (size_t)(r0 + i) * 256);
#pragma unroll
    for (int j = 0; j < 4; j++) B[j] = (const float4*)(encsc + (size_t)(b * 128 + s0 + j) * 256);
    float acc[4][4];
#pragma unroll
    for (int i = 0; i < 4; i++)
#pragma unroll
      for (int j = 0; j < 4; j++) acc[i][j] = 0.f;
    for (int k = 0; k < 64; k++) {
      float4 a[4], bb[4];
#pragma unroll
      for (int i = 0; i < 4; i++) a[i] = A[i][k];
#pragma unroll
      for (int j = 0; j < 4; j++) bb[j] = B[j][k];
#pragma unroll
      for (int i = 0; i < 4; i++)
#pragma unroll
        for (int j = 0; j < 4; j++)
          acc[i][j] += a[i].x * bb[j].x + a[i].y * bb[j].y + a[i].z * bb[j].z + a[i].w * bb[j].w;
    }
#pragma unroll
    for (int i = 0; i < 4; i++)
#pragma unroll
      for (int j = 0; j < 4; j++) {
        float v = acc[i][j] + (encidx[b * 128 + s0 + j] == 0 ? -1000.f : 0.f);
        psic[(size_t)(r0 + i) * 128 + s0 + j] = v;
      }
    return;
  }
  // ---- psi_g branch
  int nc = q % 250, mt = q / 250;
  int wid = tid >> 6, lane = tid & 63;
  int wm = wid >> 1, wn = wid & 1;
  int quad = lane >> 4, l15 = lane & 15;
  f32x4_t acc[4][4];
#pragma unroll
  for (int i = 0; i < 4; i++)
#pragma unroll
    for (int j = 0; j < 4; j++) acc[i][j] = (f32x4_t){0.f, 0.f, 0.f, 0.f};

#define STAGE_MID(buf, kt) do {                                                            \
    _Pragma("unroll")                                                                      \
    for (int u = 0; u < 4; u++) {                                                          \
      int c = u * 256 + tid;                                                               \
      int row = c >> 3;                                                                    \
      int ko = ((c & 7) ^ (row & 7)) * 8;                                                  \
      __builtin_amdgcn_global_load_lds(                                                    \
          (const __attribute__((address_space(1))) unsigned int*)(S16 + (size_t)(mt * 128 + row) * 256 + (kt) * 64 + ko), \
          (__attribute__((address_space(3))) unsigned int*)(&lA[buf][c * 8]), 16, 0, 0);   \
      __builtin_amdgcn_global_load_lds(                                                    \
          (const __attribute__((address_space(1))) unsigned int*)(WG16 + (size_t)(nc * 128 + row) * 256 + (kt) * 64 + ko), \
          (__attribute__((address_space(3))) unsigned int*)(&lB[buf][c * 8]), 16, 0, 0);   \
    }                                                                                      \
  } while (0)

  STAGE_MID(0, 0);
  __syncthreads();
  for (int kt = 0; kt < 4; kt++) {
    int cur = kt & 1;
    if (kt < 3) STAGE_MID(cur ^ 1, kt + 1);
#pragma unroll
    for (int ks = 0; ks < 2; ks++) {
      bf16x8_t af[4], bfr[4];
      int slot = ((ks * 4 + quad) ^ (l15 & 7)) * 8;
#pragma unroll
      for (int i = 0; i < 4; i++) af[i] = *(const bf16x8_t*)(&lA[cur][(wm * 64 + i * 16 + l15) * 64 + slot]);
#pragma unroll
      for (int j = 0; j < 4; j++) bfr[j] = *(const bf16x8_t*)(&lB[cur][(wn * 64 + j * 16 + l15) * 64 + slot]);
#pragma unroll
      for (int i = 0; i < 4; i++)
#pragma unroll
        for (int j = 0; j < 4; j++)
          acc[i][j] = __builtin_amdgcn_mfma_f32_16x16x32_bf16(af[i], bfr[j], acc[i][j], 0, 0, 0);
    }
    __syncthreads();
  }
#undef STAGE_MID
  float bj[4];
#pragma unroll
  for (int j = 0; j < 4; j++) bj[j] = wgb[nc * 128 + wn * 64 + j * 16 + l15];
#pragma unroll
  for (int i = 0; i < 4; i++) {
#pragma unroll
    for (int p = 0; p < 4; p++) {
      int rg = mt * 128 + wm * 64 + i * 16 + quad * 4 + p;
      size_t base = (size_t)rg * 32000 + nc * 128 + wn * 64 + l15;
#pragma unroll
      for (int j = 0; j < 4; j++)
        pe16[base + j * 16] = f2bf(expf(acc[i][j][p] + bj[j]));
    }
  }
}

// pass B: register-resident stream. E = exp(psi_g) bf16; Z = sum(E) + sum(exp(psi_c)).
// Defensive shift D = max(Mc-30, 0) keeps the psi_c exps in fp32 range;
// algebraically identical to the reference softmax. One block per row.
__global__ __launch_bounds__(256) void k_pb(const unsigned short* __restrict__ pe16,
                                            const float* __restrict__ psic,
                                            const int* __restrict__ encidx,
                                            float* __restrict__ outp) {
  __shared__ float red[8];
  int r = blockIdx.x;          // 0..2047
  int b = r >> 6;
  int tid = threadIdx.x;
  int wid = tid >> 6, lane = tid & 63;
  const unsigned short* prow = pe16 + (size_t)r * 32000;
  float* orow = outp + (size_t)r * VT_;
  int4 ev[16];
#pragma unroll
  for (int u = 0; u < 16; u++) {
    int c8 = u * 256 + tid;
    if (c8 < 4000) ev[u] = *(const int4*)(prow + c8 * 8);
    else ev[u] = (int4){0, 0, 0, 0};
  }
  float sumE = 0.f;
#pragma unroll
  for (int u = 0; u < 16; u++) {
    unsigned int xs0 = (unsigned int)ev[u].x, xs1 = (unsigned int)ev[u].y;
    unsigned int xs2 = (unsigned int)ev[u].z, xs3 = (unsigned int)ev[u].w;
    sumE += bfbits(xs0 << 16) + bfbits(xs0 & 0xffff0000u);
    sumE += bfbits(xs1 << 16) + bfbits(xs1 & 0xffff0000u);
    sumE += bfbits(xs2 << 16) + bfbits(xs2 & 0xffff0000u);
    sumE += bfbits(xs3 << 16) + bfbits(xs3 & 0xffff0000u);
  }
  // block-reduce sumE -> red[0..3]; psi_c max -> red[4..7]
  float t = sumE;
#pragma unroll
  for (int off = 32; off >= 1; off >>= 1) t += __shfl_xor(t, off);
  if (lane == 0) red[wid] = t;
  float pc = (tid < 128) ? psic[(size_t)r * 128 + tid] : -3e38f;
  float mv = pc;
#pragma unroll
  for (int off = 32; off >= 1; off >>= 1) mv = fmaxf(mv, __shfl_xor(mv, off));
  if (lane == 0) red[4 + wid] = mv;
  __syncthreads();
  float sumEt = red[0] + red[1] + red[2] + red[3];
  float Mc = fmaxf(fmaxf(red[4], red[5]), fmaxf(red[6], red[7]));
  float D = fmaxf(Mc - 30.f, 0.f);
  float w = expf(-D);
  __syncthreads();
  float ec = (tid < 128) ? expf(pc - D) : 0.f;
  float zt = ec;
#pragma unroll
  for (int off = 32; off >= 1; off >>= 1) zt += __shfl_xor(zt, off);
  if (lane == 0) red[wid] = zt;
  __syncthreads();
  float Z = w * sumEt + (red[0] + red[1] + red[2] + red[3]);
  float gs = w / Z;
  // stream out: p_g = E * gs
#pragma unroll 2
  for (int u = 0; u < 16; u++) {
    int c8 = u * 256 + tid;
    if (c8 < 4000) {
      int c0 = c8 * 8;
      unsigned int xs0 = (unsigned int)ev[u].x, xs1 = (unsigned int)ev[u].y;
      unsigned int xs2 = (unsigned int)ev[u].z, xs3 = (unsigned int)ev[u].w;
      float4 o0, o1;
      o0.x = bfbits(xs0 << 16) * gs;         o0.y = bfbits(xs0 & 0xffff0000u) * gs;
      o0.z = bfbits(xs1 << 16) * gs;         o0.w = bfbits(xs1 & 0xffff0000u) * gs;
      o1.x = bfbits(xs2 << 16) * gs;         o1.y = bfbits(xs2 & 0xffff0000u) * gs;
      o1.z = bfbits(xs3 << 16) * gs;         o1.w = bfbits(xs3 & 0xffff0000u) * gs;
      *(float4*)(orow + c0) = o0;
      *(float4*)(orow + c0 + 4) = o1;
    }
  }
  if (tid < 100) orow[32000 + tid] = 1e-4f;
  __syncthreads();   // drains vmem: streamed stores visible in L2 before RMW
  if (tid < 128) {
    int idx = encidx[b * 128 + tid];
    atomicAdd(&orow[idx], ec / Z);
  }
}

// ---------------------------------------------------------------- launch
extern "C" void kernel_launch(void* const* d_in, const int* in_sizes, int n_in,
                              void* d_out, int out_size, void* d_ws, size_t ws_size,
                              hipStream_t stream) {
  (void)in_sizes; (void)n_in; (void)out_size; (void)ws_size;
  const int*   inputs  = (const int*)d_in[0];
  const float* encoded = (const float*)d_in[1];
  const int*   encidx  = (const int*)d_in[2];
  const float* bridge  = (const float*)d_in[3];
  const float* embed   = (const float*)d_in[4];
  const float* wih     = (const float*)d_in[5];
  const float* whh     = (const float*)d_in[6];
  const float* bih     = (const float*)d_in[7];
  const float* bhh     = (const float*)d_in[8];
  const float* wg      = (const float*)d_in[9];
  const float* wgb     = (const float*)d_in[10];
  const float* wo      = (const float*)d_in[11];
  const float* wob     = (const float*)d_in[12];
  float* out = (float*)d_out;

  char* ws = (char*)d_ws;
  size_t off = 0;
  auto alloc = [&](size_t bytes) -> void* {
    void* p = ws + off;
    off += (bytes + 255) & ~(size_t)255;
    return p;
  };
  unsigned short* WG16  = (unsigned short*)alloc((size_t)32000 * 256 * 2);
  unsigned short* WHH16 = (unsigned short*)alloc((size_t)768 * 256 * 2);
  float* S32            = (float*)alloc((size_t)2048 * 256 * 4);
  unsigned short* S16   = (unsigned short*)alloc((size_t)2048 * 256 * 2);
  float* ENCSC          = (float*)alloc((size_t)4096 * 256 * 4);
  float* ENCIH          = (float*)alloc((size_t)4096 * 768 * 4);
  float* XG             = (float*)alloc((size_t)2048 * 768 * 4);
  float* S0             = (float*)alloc((size_t)32 * 256 * 4);
  float* PSIC           = (float*)alloc((size_t)2048 * 128 * 4);
  unsigned short* PE16  = (unsigned short*)alloc((size_t)2048 * 32000 * 2);

  k_pre<<<5804, 256, 0, stream>>>(wg, WG16, whh, WHH16, encoded, wo, wob, ENCSC,
                                  bridge, S0, embed, inputs, wih, bih, XG,
                                  encidx, ENCIH);
  k_seq<<<32, 768, 0, stream>>>(WHH16, bhh, XG, ENCSC, ENCIH, encidx, inputs, S0, S32, S16);
  k_mid<<<4064, 256, 0, stream>>>(S16, WG16, wgb, PE16, S32, ENCSC, encidx, PSIC);
  k_pb<<<2048, 256, 0, stream>>>(PE16, PSIC, encidx, out);
}

// Round 5
// 776.241 us; speedup vs baseline: 1.5998x; 1.0783x over previous
//
#include <hip/hip_runtime.h>
#include <math.h>
#include <stdint.h>

// Problem constants
static const int VOC  = 32000;
static const int VT_  = 32100;

typedef __attribute__((ext_vector_type(8))) short bf16x8_t;
typedef __attribute__((ext_vector_type(4))) float f32x4_t;

__device__ __forceinline__ unsigned short f2bf(float f) {
  union { float f; unsigned int u; } v; v.f = f;
  unsigned int u = v.u;
  u = u + 0x7FFFu + ((u >> 16) & 1u);   // RNE
  return (unsigned short)(u >> 16);
}
__device__ __forceinline__ float bf2f(unsigned short u) {
  union { unsigned int i; float f; } w; w.i = ((unsigned int)u) << 16; return w.f;
}
__device__ __forceinline__ float bfbits(unsigned int u) {
  union { unsigned int i; float f; } w; w.i = u; return w.f;
}
// position of the j-th set bit (ascending) across the 128-bit mask (m0,m1)
__device__ __forceinline__ int nth_set(unsigned long long m0, unsigned long long m1, int j) {
  int c0 = __popcll(m0);
  unsigned long long m = m0; int base = 0;
  if (j >= c0) { j -= c0; m = m1; base = 64; }
  for (int k = 0; k < j; k++) m &= m - 1;
  return base + (__ffsll((long long)m) - 1);
}

// ------------------------------------------------ k_pre0: all dtype conversions
//   [0,1024)     wg -> WG16 (bf16)
//   [1024,1036)  whh -> WHH16
//   [1036,1292)  encoded -> EH, EL (hi/lo split bf16)
//   [1292,1300)  wo -> WOH, WOL (hi/lo split)
//   [1300,1312)  wih[:, 0:256] -> WIH16 [768][256] bf16
//   [1312,1440)  X16[r] = bf16(embed[inputs[r]])  [2048][256]
__global__ __launch_bounds__(256) void k_pre0(
    const float* __restrict__ wg, unsigned short* __restrict__ WG16,
    const float* __restrict__ whh, unsigned short* __restrict__ WHH16,
    const float* __restrict__ enc, unsigned short* __restrict__ EH,
    unsigned short* __restrict__ EL,
    const float* __restrict__ wo, unsigned short* __restrict__ WOH,
    unsigned short* __restrict__ WOL,
    const float* __restrict__ wih, unsigned short* __restrict__ WIH16,
    const float* __restrict__ embed, const int* __restrict__ inputs,
    unsigned short* __restrict__ X16) {
  int q = blockIdx.x, tid = threadIdx.x;
  if (q < 1024) {
    for (int i = q * 256 + tid; i < 2048000; i += 1024 * 256) {
      float4 f = ((const float4*)wg)[i];
      ushort4 o;
      o.x = f2bf(f.x); o.y = f2bf(f.y); o.z = f2bf(f.z); o.w = f2bf(f.w);
      ((ushort4*)WG16)[i] = o;
    }
  } else if (q < 1036) {
    for (int i = (q - 1024) * 256 + tid; i < 49152; i += 12 * 256) {
      float4 f = ((const float4*)whh)[i];
      ushort4 o;
      o.x = f2bf(f.x); o.y = f2bf(f.y); o.z = f2bf(f.z); o.w = f2bf(f.w);
      ((ushort4*)WHH16)[i] = o;
    }
  } else if (q < 1292) {
    for (int i = (q - 1036) * 256 + tid; i < 524288; i += 256 * 256) {
      float4 f = ((const float4*)enc)[i];
      ushort4 h, l;
      h.x = f2bf(f.x); l.x = f2bf(f.x - bf2f(h.x));
      h.y = f2bf(f.y); l.y = f2bf(f.y - bf2f(h.y));
      h.z = f2bf(f.z); l.z = f2bf(f.z - bf2f(h.z));
      h.w = f2bf(f.w); l.w = f2bf(f.w - bf2f(h.w));
      ((ushort4*)EH)[i] = h;
      ((ushort4*)EL)[i] = l;
    }
  } else if (q < 1300) {
    for (int i = (q - 1292) * 256 + tid; i < 32768; i += 8 * 256) {
      float4 f = ((const float4*)wo)[i];
      ushort4 h, l;
      h.x = f2bf(f.x); l.x = f2bf(f.x - bf2f(h.x));
      h.y = f2bf(f.y); l.y = f2bf(f.y - bf2f(h.y));
      h.z = f2bf(f.z); l.z = f2bf(f.z - bf2f(h.z));
      h.w = f2bf(f.w); l.w = f2bf(f.w - bf2f(h.w));
      ((ushort4*)WOH)[i] = h;
      ((ushort4*)WOL)[i] = l;
    }
  } else if (q < 1312) {
    for (int g = (q - 1300) * 256 + tid; g < 49152; g += 12 * 256) {
      int row = g >> 6, col = g & 63;
      float4 f = ((const float4*)(wih + (size_t)row * 768))[col];
      ushort4 o;
      o.x = f2bf(f.x); o.y = f2bf(f.y); o.z = f2bf(f.z); o.w = f2bf(f.w);
      ((ushort4*)X16)[0]; // no-op; keep branch shape
      ((ushort4*)WIH16)[g] = o;
    }
  } else {
    for (int g = (q - 1312) * 256 + tid; g < 131072; g += 128 * 256) {
      int r = g >> 6, col = g & 63;
      float4 f = ((const float4*)(embed + (size_t)inputs[r] * 256))[col];
      ushort4 o;
      o.x = f2bf(f.x); o.y = f2bf(f.y); o.z = f2bf(f.z); o.w = f2bf(f.w);
      ((ushort4*)X16)[g] = o;
    }
  }
}

// ------------------------------------------------ k_pre1: MFMA GEMMs + s0 + encih
//   [0,256)     ENCSC = tanh(enc @ Wo^T + b) via split bf16x3 MFMA (fp32-accurate)
//   [256,640)   XG = X16 @ WIH16^T + b_ih via bf16 MFMA
//   [640,672)   s0 (fp32 VALU)
//   [672,4768)  encih (flag-gated fp32 VALU)
__global__ __launch_bounds__(256) void k_pre1(
    const unsigned short* __restrict__ EH, const unsigned short* __restrict__ EL,
    const unsigned short* __restrict__ WOH, const unsigned short* __restrict__ WOL,
    const float* __restrict__ wob, float* __restrict__ ENCSC,
    const unsigned short* __restrict__ X16, const unsigned short* __restrict__ WIH16,
    const float* __restrict__ bih, float* __restrict__ XG,
    const float* __restrict__ enc, const float* __restrict__ bridge,
    float* __restrict__ S0,
    const float* __restrict__ wih, const int* __restrict__ encidx,
    const int* __restrict__ inputs, float* __restrict__ ENCIH) {
  __shared__ int flag;
  int q = blockIdx.x, tid = threadIdx.x;
  int wid = tid >> 6, lane = tid & 63;
  int wm = wid >> 1, wn = wid & 1;
  int quad = lane >> 4, l15 = lane & 15;
  if (q < 256) {
    // ---- enc split-MFMA: M=4096, N=256, K=512; 64x64 tile
    int bm = q >> 2, bn = q & 3;
    int r0 = bm * 64 + wm * 32, n0 = bn * 64 + wn * 32;
    f32x4_t acc[2][2];
#pragma unroll
    for (int i = 0; i < 2; i++)
#pragma unroll
      for (int j = 0; j < 2; j++) acc[i][j] = (f32x4_t){0.f, 0.f, 0.f, 0.f};
    for (int kc = 0; kc < 16; kc++) {
      int ko = kc * 32 + quad * 8;
      bf16x8_t ah[2], al[2], bh[2], bl[2];
#pragma unroll
      for (int i = 0; i < 2; i++) {
        size_t off = (size_t)(r0 + i * 16 + l15) * 512 + ko;
        ah[i] = *(const bf16x8_t*)(EH + off);
        al[i] = *(const bf16x8_t*)(EL + off);
      }
#pragma unroll
      for (int j = 0; j < 2; j++) {
        size_t off = (size_t)(n0 + j * 16 + l15) * 512 + ko;
        bh[j] = *(const bf16x8_t*)(WOH + off);
        bl[j] = *(const bf16x8_t*)(WOL + off);
      }
#pragma unroll
      for (int i = 0; i < 2; i++)
#pragma unroll
        for (int j = 0; j < 2; j++) {
          acc[i][j] = __builtin_amdgcn_mfma_f32_16x16x32_bf16(ah[i], bh[j], acc[i][j], 0, 0, 0);
          acc[i][j] = __builtin_amdgcn_mfma_f32_16x16x32_bf16(ah[i], bl[j], acc[i][j], 0, 0, 0);
          acc[i][j] = __builtin_amdgcn_mfma_f32_16x16x32_bf16(al[i], bh[j], acc[i][j], 0, 0, 0);
        }
    }
#pragma unroll
    for (int i = 0; i < 2; i++)
#pragma unroll
      for (int j = 0; j < 2; j++)
#pragma unroll
        for (int p = 0; p < 4; p++) {
          int row = r0 + i * 16 + quad * 4 + p;
          int col = n0 + j * 16 + l15;
          ENCSC[(size_t)row * 256 + col] = tanhf(acc[i][j][p] + wob[col]);
        }
  } else if (q < 640) {
    // ---- xg MFMA: M=2048, N=768, K=256; 64x64 tile
    int p2 = q - 256;
    int bm = p2 & 31, bn = p2 >> 5;
    int r0 = bm * 64 + wm * 32, n0 = bn * 64 + wn * 32;
    f32x4_t acc[2][2];
#pragma unroll
    for (int i = 0; i < 2; i++)
#pragma unroll
      for (int j = 0; j < 2; j++) acc[i][j] = (f32x4_t){0.f, 0.f, 0.f, 0.f};
    for (int kc = 0; kc < 8; kc++) {
      int ko = kc * 32 + quad * 8;
      bf16x8_t a[2], b[2];
#pragma unroll
      for (int i = 0; i < 2; i++)
        a[i] = *(const bf16x8_t*)(X16 + (size_t)(r0 + i * 16 + l15) * 256 + ko);
#pragma unroll
      for (int j = 0; j < 2; j++)
        b[j] = *(const bf16x8_t*)(WIH16 + (size_t)(n0 + j * 16 + l15) * 256 + ko);
#pragma unroll
      for (int i = 0; i < 2; i++)
#pragma unroll
        for (int j = 0; j < 2; j++)
          acc[i][j] = __builtin_amdgcn_mfma_f32_16x16x32_bf16(a[i], b[j], acc[i][j], 0, 0, 0);
    }
#pragma unroll
    for (int i = 0; i < 2; i++)
#pragma unroll
      for (int j = 0; j < 2; j++)
#pragma unroll
        for (int p = 0; p < 4; p++) {
          int row = r0 + i * 16 + quad * 4 + p;
          int col = n0 + j * 16 + l15;
          XG[(size_t)row * 768 + col] = acc[i][j][p] + bih[col];
        }
  } else if (q < 672) {
    // ---- s0
    int b = q - 640, h = tid;
    const float4* a4 = (const float4*)(enc + ((size_t)b * 128 + 127) * 512);
    const float4* w4 = (const float4*)(bridge + (size_t)h * 512);
    float acc = 0.f;
    for (int k = 0; k < 128; k++) {
      float4 a = a4[k], w = w4[k];
      acc += a.x * w.x + a.y * w.y + a.z * w.z + a.w * w.w;
    }
    S0[b * 256 + h] = acc;
  } else {
    // ---- encih (flag-gated)
    int bs = q - 672;
    int b = bs >> 7;
    int idx = encidx[bs];
    if (tid < 64) {
      unsigned long long m = __ballot(inputs[b * 64 + tid] == idx);
      if (tid == 0) flag = (m != 0ULL);
    }
    __syncthreads();
    if (!flag) return;
    const float4* e4 = (const float4*)(enc + (size_t)bs * 512);
    for (int d = tid; d < 768; d += 256) {
      const float4* w4 = (const float4*)(wih + (size_t)d * 768 + 256);
      float acc = 0.f;
      for (int k = 0; k < 128; k++) {
        float4 e = e4[k], w = w4[k];
        acc += e.x * w.x + e.y * w.y + e.z * w.z + e.w * w.w;
      }
      ENCIH[(size_t)bs * 768 + d] = acc;
    }
  }
}

// -------------------------------------------------------- sequential GRU (unchanged)
__global__ __launch_bounds__(768, 1) void k_seq(
    const unsigned short* __restrict__ whb,  // [768][256] bf16 W_hh
    const float* __restrict__ bhh,
    const float* __restrict__ xg, const float* __restrict__ encsc,
    const float* __restrict__ encih, const int* __restrict__ encidx,
    const int* __restrict__ inputs, const float* __restrict__ s0,
    float* __restrict__ S32, unsigned short* __restrict__ S16) {
  __shared__ float sbuf[256];
  __shared__ __align__(16) unsigned short sb16[256];
  __shared__ float ghp[768];
  __shared__ float psis[128];
  __shared__ int eidx_sh[128];
  __shared__ int inp_sh[64];
  __shared__ unsigned long long mmask[64][2];
  __shared__ __align__(16) unsigned short wlds[73728];  // 144 KB
  int b = blockIdx.x;
  int tid = threadIdx.x;
  int wid = tid >> 6, lane = tid & 63;
  int quad = lane >> 4, l15 = lane & 15;
  int n0 = wid * 64;
  int h = tid;
#pragma unroll
  for (int c = 0; c < 4; c++)
#pragma unroll
    for (int kt2 = 0; kt2 < 3; kt2++) {
      int4 v = *(const int4*)(whb + (size_t)(n0 + c * 16 + l15) * 256 + 160 + kt2 * 32 + quad * 8);
      *(int4*)(wlds + wid * 6144 + (c * 3 + kt2) * 512 + (l15 * 4 + quad) * 8) = v;
    }
  bf16x8_t wf[20];
#pragma unroll
  for (int c = 0; c < 4; c++)
#pragma unroll
    for (int kt = 0; kt < 5; kt++)
      wf[c * 5 + kt] = *(const bf16x8_t*)(whb + (size_t)(n0 + c * 16 + l15) * 256 + kt * 32 + quad * 8);
  float bR = 0.f, bZ = 0.f, bN = 0.f, ctxR = 0.f, ctxZ = 0.f, ctxN = 0.f;
  if (tid < 256) {
    bR = bhh[h]; bZ = bhh[256 + h]; bN = bhh[512 + h];
    float v = s0[b * 256 + tid];
    sbuf[tid] = v;
    sb16[tid] = f2bf(v);
  }
  if (tid < 128) eidx_sh[tid] = encidx[b * 128 + tid];
  if (tid < 64) inp_sh[tid] = inputs[b * 64 + tid];
  __syncthreads();
  if (tid < 128) {
    int e = eidx_sh[tid];
    for (int t = 0; t < 64; t++) {
      unsigned long long bal = __ballot(e == inp_sh[t]);
      if (lane == 0) mmask[t][wid] = bal;
    }
  }
  __syncthreads();
  for (int t = 0; t < 64; t++) {
    int r = b * 64 + t;
    float xr0 = 0.f, xr1 = 0.f, xr2 = 0.f;
    if (tid < 256) {
      const float* xr = xg + (size_t)r * 768;
      xr0 = xr[h]; xr1 = xr[256 + h]; xr2 = xr[512 + h];
    }
    f32x4_t a0 = {0.f,0.f,0.f,0.f}, a1 = {0.f,0.f,0.f,0.f};
    f32x4_t a2 = {0.f,0.f,0.f,0.f}, a3 = {0.f,0.f,0.f,0.f};
#pragma unroll
    for (int kt = 0; kt < 5; kt++) {
      bf16x8_t af = *(const bf16x8_t*)(sb16 + kt * 32 + quad * 8);
      a0 = __builtin_amdgcn_mfma_f32_16x16x32_bf16(af, wf[ 0 + kt], a0, 0, 0, 0);
      a1 = __builtin_amdgcn_mfma_f32_16x16x32_bf16(af, wf[ 5 + kt], a1, 0, 0, 0);
      a2 = __builtin_amdgcn_mfma_f32_16x16x32_bf16(af, wf[10 + kt], a2, 0, 0, 0);
      a3 = __builtin_amdgcn_mfma_f32_16x16x32_bf16(af, wf[15 + kt], a3, 0, 0, 0);
    }
#pragma unroll
    for (int kt2 = 0; kt2 < 3; kt2++) {
      bf16x8_t af = *(const bf16x8_t*)(sb16 + (5 + kt2) * 32 + quad * 8);
      const unsigned short* wb = wlds + wid * 6144 + kt2 * 512 + (l15 * 4 + quad) * 8;
      a0 = __builtin_amdgcn_mfma_f32_16x16x32_bf16(af, *(const bf16x8_t*)(wb +    0), a0, 0, 0, 0);
      a1 = __builtin_amdgcn_mfma_f32_16x16x32_bf16(af, *(const bf16x8_t*)(wb + 1536), a1, 0, 0, 0);
      a2 = __builtin_amdgcn_mfma_f32_16x16x32_bf16(af, *(const bf16x8_t*)(wb + 3072), a2, 0, 0, 0);
      a3 = __builtin_amdgcn_mfma_f32_16x16x32_bf16(af, *(const bf16x8_t*)(wb + 4608), a3, 0, 0, 0);
    }
    if (lane < 16) {
      ghp[n0 +      lane] = a0[0];
      ghp[n0 + 16 + lane] = a1[0];
      ghp[n0 + 32 + lane] = a2[0];
      ghp[n0 + 48 + lane] = a3[0];
    }
    __syncthreads();                                   // B1: gh complete
    if (tid < 256) {
      float hr = ghp[h] + bR;
      float hz = ghp[256 + h] + bZ;
      float hn = ghp[512 + h] + bN;
      float gr = xr0 + ctxR;
      float gz = xr1 + ctxZ;
      float gn = xr2 + ctxN;
      float rgate = 1.f / (1.f + expf(-(gr + hr)));
      float zgate = 1.f / (1.f + expf(-(gz + hz)));
      float ngate = tanhf(gn + rgate * hn);
      float sold = sbuf[h];
      float snew = (1.f - zgate) * ngate + zgate * sold;
      unsigned short u16 = f2bf(snew);
      S32[(size_t)r * 256 + h] = snew;
      S16[(size_t)r * 256 + h] = u16;
      sbuf[h] = snew;
      sb16[h] = u16;
    }
    __syncthreads();                                   // B2: s_t complete
    if (t == 63) break;
    unsigned long long m0 = mmask[t][0], m1 = mmask[t][1];
    int mc = __popcll(m0) + __popcll(m1);
    if (mc > 0) {                                      // uniform branch
      for (int j = wid; j < mc; j += 12) {
        int s = nth_set(m0, m1, j);
        const float4* e4 = (const float4*)(encsc + (size_t)(b * 128 + s) * 256);
        float4 ev = e4[lane];
        float4 sv = ((const float4*)sbuf)[lane];
        float v = ev.x * sv.x + ev.y * sv.y + ev.z * sv.z + ev.w * sv.w;
#pragma unroll
        for (int off = 32; off >= 1; off >>= 1) v += __shfl_down(v, off);
        if (lane == 0) psis[j] = v + (eidx_sh[s] == 0 ? -1000.f : 0.f);
      }
      __syncthreads();
      if (tid == 0) {
        float mx = -3e38f;
        for (int j = 0; j < mc; j++) mx = fmaxf(mx, psis[j]);
        if (mx < -500.f) {
          for (int j = 0; j < mc; j++) psis[j] = 0.f;
        } else {
          float ss = 0.f;
          for (int j = 0; j < mc; j++) { float e = expf(psis[j] - mx); psis[j] = e; ss += e; }
          float rs = 1.f / ss;
          for (int j = 0; j < mc; j++) psis[j] *= rs;
        }
      }
      __syncthreads();
      if (tid < 256) {
        ctxR = 0.f; ctxZ = 0.f; ctxN = 0.f;
        unsigned long long mm0 = m0, mm1 = m1;
        for (int j = 0; j < mc; j++) {
          int s;
          if (mm0) { s = __ffsll((long long)mm0) - 1; mm0 &= mm0 - 1; }
          else     { s = 64 + __ffsll((long long)mm1) - 1; mm1 &= mm1 - 1; }
          float c = psis[j];
          const float* e = encih + (size_t)(b * 128 + s) * 768;
          ctxR += c * e[h]; ctxZ += c * e[256 + h]; ctxN += c * e[512 + h];
        }
      }
    } else if (tid < 256) {
      ctxR = 0.f; ctxZ = 0.f; ctxN = 0.f;
    }
  }
}

// -------------------------------------------------- k_mid: psi_g GEMM (B-resident) + psi_c
// blocks [0,250): per nc column-chunk; WG16 tile [128][256] staged ONCE in LDS
// (64 KB), loop over 16 mt tiles restaging only the S16 A-tile (L3-hot).
// Writes E = bf16(exp(psi)). XOR-swizzled chunks (3-bit within 8-chunk groups).
// blocks [250,314): psic = S32 x ENCSC^T + pad mask (fp32 precision kept).
__global__ __launch_bounds__(256) void k_mid(const unsigned short* __restrict__ S16,
                                             const unsigned short* __restrict__ WG16,
                                             const float* __restrict__ wgb,
                                             unsigned short* __restrict__ pe16,
                                             const float* __restrict__ S32,
                                             const float* __restrict__ encsc,
                                             const int* __restrict__ encidx,
                                             float* __restrict__ psic) {
  int q = blockIdx.x;
  int tid = threadIdx.x;
  if (q >= 250) {
    // ---- psic branch
    int q2 = q - 250;
    int b = q2 >> 1, ny = q2 & 1;
    int ti = tid & 15, tj = tid >> 4;
    int r0 = b * 64 + ti * 4;
    int s0 = ny * 64 + tj * 4;
    const float4* A[4]; const float4* B[4];
#pragma unroll
    for (int i = 0; i < 4; i++) A[i] = (const float4*)(S32 + (size_t)(r0 + i) * 256);
#pragma unroll
    for (int j = 0; j < 4; j++) B[j] = (const float4*)(encsc + (size_t)(b * 128 + s0 + j) * 256);
    float acc[4][4];
#pragma unroll
    for (int i = 0; i < 4; i++)
#pragma unroll
      for (int j = 0; j < 4; j++) acc[i][j] = 0.f;
    for (int k = 0; k < 64; k++) {
      float4 a[4], bb[4];
#pragma unroll
      for (int i = 0; i < 4; i++) a[i] = A[i][k];
#pragma unroll
      for (int j = 0; j < 4; j++) bb[j] = B[j][k];
#pragma unroll
      for (int i = 0; i < 4; i++)
#pragma unroll
        for (int j = 0; j < 4; j++)
          acc[i][j] += a[i].x * bb[j].x + a[i].y * bb[j].y + a[i].z * bb[j].z + a[i].w * bb[j].w;
    }
#pragma unroll
    for (int i = 0; i < 4; i++)
#pragma unroll
      for (int j = 0; j < 4; j++) {
        float v = acc[i][j] + (encidx[b * 128 + s0 + j] == 0 ? -1000.f : 0.f);
        psic[(size_t)(r0 + i) * 128 + s0 + j] = v;
      }
    return;
  }
  // ---- psi_g branch: B-resident over mt loop
  __shared__ unsigned short lB[128 * 256];   // 64 KB
  __shared__ unsigned short lA[128 * 256];   // 64 KB
  int nc = q;
  int wid = tid >> 6, lane = tid & 63;
  int wm = wid >> 1, wn = wid & 1;
  int quad = lane >> 4, l15 = lane & 15;
  // stage B once (swizzled source chunks)
#pragma unroll
  for (int u = 0; u < 16; u++) {
    int c = u * 256 + tid;
    int row = c >> 5, ch = c & 31;
    int sch = (ch & 24) | ((ch & 7) ^ (row & 7));
    __builtin_amdgcn_global_load_lds(
        (const __attribute__((address_space(1))) unsigned int*)(WG16 + (size_t)(nc * 128 + row) * 256 + sch * 8),
        (__attribute__((address_space(3))) unsigned int*)(lB + c * 8), 16, 0, 0);
  }
  float bj[4];
#pragma unroll
  for (int j = 0; j < 4; j++) bj[j] = wgb[nc * 128 + wn * 64 + j * 16 + l15];
  for (int mt = 0; mt < 16; mt++) {
    // stage A tile for this mt
#pragma unroll
    for (int u = 0; u < 16; u++) {
      int c = u * 256 + tid;
      int row = c >> 5, ch = c & 31;
      int sch = (ch & 24) | ((ch & 7) ^ (row & 7));
      __builtin_amdgcn_global_load_lds(
          (const __attribute__((address_space(1))) unsigned int*)(S16 + (size_t)(mt * 128 + row) * 256 + sch * 8),
          (__attribute__((address_space(3))) unsigned int*)(lA + c * 8), 16, 0, 0);
    }
    __syncthreads();   // A (and on mt=0, B) staged
    f32x4_t acc[4][4];
#pragma unroll
    for (int i = 0; i < 4; i++)
#pragma unroll
      for (int j = 0; j < 4; j++) acc[i][j] = (f32x4_t){0.f, 0.f, 0.f, 0.f};
#pragma unroll
    for (int kc = 0; kc < 8; kc++) {
      int g = kc * 4 + quad;
      int slotoff = ((g & 24) | ((g & 7) ^ (l15 & 7))) * 8;
      bf16x8_t af[4], bfr[4];
#pragma unroll
      for (int i = 0; i < 4; i++)
        af[i] = *(const bf16x8_t*)(lA + (wm * 64 + i * 16 + l15) * 256 + slotoff);
#pragma unroll
      for (int j = 0; j < 4; j++)
        bfr[j] = *(const bf16x8_t*)(lB + (wn * 64 + j * 16 + l15) * 256 + slotoff);
#pragma unroll
      for (int i = 0; i < 4; i++)
#pragma unroll
        for (int j = 0; j < 4; j++)
          acc[i][j] = __builtin_amdgcn_mfma_f32_16x16x32_bf16(af[i], bfr[j], acc[i][j], 0, 0, 0);
    }
    // epilogue for this mt
#pragma unroll
    for (int i = 0; i < 4; i++)
#pragma unroll
      for (int p = 0; p < 4; p++) {
        int rg = mt * 128 + wm * 64 + i * 16 + quad * 4 + p;
        size_t base = (size_t)rg * 32000 + nc * 128 + wn * 64 + l15;
#pragma unroll
        for (int j = 0; j < 4; j++)
          pe16[base + j * 16] = f2bf(expf(acc[i][j][p] + bj[j]));
      }
    __syncthreads();   // all reads of lA done before next overwrite
  }
}

// pass B: register-resident stream (unchanged from round 4).
__global__ __launch_bounds__(256) void k_pb(const unsigned short* __restrict__ pe16,
                                            const float* __restrict__ psic,
                                            const int* __restrict__ encidx,
                                            float* __restrict__ outp) {
  __shared__ float red[8];
  int r = blockIdx.x;          // 0..2047
  int b = r >> 6;
  int tid = threadIdx.x;
  int wid = tid >> 6, lane = tid & 63;
  const unsigned short* prow = pe16 + (size_t)r * 32000;
  float* orow = outp + (size_t)r * VT_;
  int4 ev[16];
#pragma unroll
  for (int u = 0; u < 16; u++) {
    int c8 = u * 256 + tid;
    if (c8 < 4000) ev[u] = *(const int4*)(prow + c8 * 8);
    else ev[u] = (int4){0, 0, 0, 0};
  }
  float sumE = 0.f;
#pragma unroll
  for (int u = 0; u < 16; u++) {
    unsigned int xs0 = (unsigned int)ev[u].x, xs1 = (unsigned int)ev[u].y;
    unsigned int xs2 = (unsigned int)ev[u].z, xs3 = (unsigned int)ev[u].w;
    sumE += bfbits(xs0 << 16) + bfbits(xs0 & 0xffff0000u);
    sumE += bfbits(xs1 << 16) + bfbits(xs1 & 0xffff0000u);
    sumE += bfbits(xs2 << 16) + bfbits(xs2 & 0xffff0000u);
    sumE += bfbits(xs3 << 16) + bfbits(xs3 & 0xffff0000u);
  }
  float t = sumE;
#pragma unroll
  for (int off = 32; off >= 1; off >>= 1) t += __shfl_xor(t, off);
  if (lane == 0) red[wid] = t;
  float pc = (tid < 128) ? psic[(size_t)r * 128 + tid] : -3e38f;
  float mv = pc;
#pragma unroll
  for (int off = 32; off >= 1; off >>= 1) mv = fmaxf(mv, __shfl_xor(mv, off));
  if (lane == 0) red[4 + wid] = mv;
  __syncthreads();
  float sumEt = red[0] + red[1] + red[2] + red[3];
  float Mc = fmaxf(fmaxf(red[4], red[5]), fmaxf(red[6], red[7]));
  float D = fmaxf(Mc - 30.f, 0.f);
  float w = expf(-D);
  __syncthreads();
  float ec = (tid < 128) ? expf(pc - D) : 0.f;
  float zt = ec;
#pragma unroll
  for (int off = 32; off >= 1; off >>= 1) zt += __shfl_xor(zt, off);
  if (lane == 0) red[wid] = zt;
  __syncthreads();
  float Z = w * sumEt + (red[0] + red[1] + red[2] + red[3]);
  float gs = w / Z;
#pragma unroll 2
  for (int u = 0; u < 16; u++) {
    int c8 = u * 256 + tid;
    if (c8 < 4000) {
      int c0 = c8 * 8;
      unsigned int xs0 = (unsigned int)ev[u].x, xs1 = (unsigned int)ev[u].y;
      unsigned int xs2 = (unsigned int)ev[u].z, xs3 = (unsigned int)ev[u].w;
      float4 o0, o1;
      o0.x = bfbits(xs0 << 16) * gs;         o0.y = bfbits(xs0 & 0xffff0000u) * gs;
      o0.z = bfbits(xs1 << 16) * gs;         o0.w = bfbits(xs1 & 0xffff0000u) * gs;
      o1.x = bfbits(xs2 << 16) * gs;         o1.y = bfbits(xs2 & 0xffff0000u) * gs;
      o1.z = bfbits(xs3 << 16) * gs;         o1.w = bfbits(xs3 & 0xffff0000u) * gs;
      *(float4*)(orow + c0) = o0;
      *(float4*)(orow + c0 + 4) = o1;
    }
  }
  if (tid < 100) orow[32000 + tid] = 1e-4f;
  __syncthreads();   // drains vmem: streamed stores visible in L2 before RMW
  if (tid < 128) {
    int idx = encidx[b * 128 + tid];
    atomicAdd(&orow[idx], ec / Z);
  }
}

// ---------------------------------------------------------------- launch
extern "C" void kernel_launch(void* const* d_in, const int* in_sizes, int n_in,
                              void* d_out, int out_size, void* d_ws, size_t ws_size,
                              hipStream_t stream) {
  (void)in_sizes; (void)n_in; (void)out_size; (void)ws_size;
  const int*   inputs  = (const int*)d_in[0];
  const float* encoded = (const float*)d_in[1];
  const int*   encidx  = (const int*)d_in[2];
  const float* bridge  = (const float*)d_in[3];
  const float* embed   = (const float*)d_in[4];
  const float* wih     = (const float*)d_in[5];
  const float* whh     = (const float*)d_in[6];
  const float* bih     = (const float*)d_in[7];
  const float* bhh     = (const float*)d_in[8];
  const float* wg      = (const float*)d_in[9];
  const float* wgb     = (const float*)d_in[10];
  const float* wo      = (const float*)d_in[11];
  const float* wob     = (const float*)d_in[12];
  float* out = (float*)d_out;

  char* ws = (char*)d_ws;
  size_t off = 0;
  auto alloc = [&](size_t bytes) -> void* {
    void* p = ws + off;
    off += (bytes + 255) & ~(size_t)255;
    return p;
  };
  unsigned short* WG16  = (unsigned short*)alloc((size_t)32000 * 256 * 2);
  unsigned short* WHH16 = (unsigned short*)alloc((size_t)768 * 256 * 2);
  unsigned short* EH    = (unsigned short*)alloc((size_t)4096 * 512 * 2);
  unsigned short* EL    = (unsigned short*)alloc((size_t)4096 * 512 * 2);
  unsigned short* WOH   = (unsigned short*)alloc((size_t)256 * 512 * 2);
  unsigned short* WOL   = (unsigned short*)alloc((size_t)256 * 512 * 2);
  unsigned short* WIH16 = (unsigned short*)alloc((size_t)768 * 256 * 2);
  unsigned short* X16   = (unsigned short*)alloc((size_t)2048 * 256 * 2);
  float* S32            = (float*)alloc((size_t)2048 * 256 * 4);
  unsigned short* S16   = (unsigned short*)alloc((size_t)2048 * 256 * 2);
  float* ENCSC          = (float*)alloc((size_t)4096 * 256 * 4);
  float* ENCIH          = (float*)alloc((size_t)4096 * 768 * 4);
  float* XG             = (float*)alloc((size_t)2048 * 768 * 4);
  float* S0             = (float*)alloc((size_t)32 * 256 * 4);
  float* PSIC           = (float*)alloc((size_t)2048 * 128 * 4);
  unsigned short* PE16  = (unsigned short*)alloc((size_t)2048 * 32000 * 2);

  k_pre0<<<1440, 256, 0, stream>>>(wg, WG16, whh, WHH16, encoded, EH, EL,
                                   wo, WOH, WOL, wih, WIH16, embed, inputs, X16);
  k_pre1<<<4768, 256, 0, stream>>>(EH, EL, WOH, WOL, wob, ENCSC,
                                   X16, WIH16, bih, XG,
                                   encoded, bridge, S0, wih, encidx, inputs, ENCIH);
  k_seq<<<32, 768, 0, stream>>>(WHH16, bhh, XG, ENCSC, ENCIH, encidx, inputs, S0, S32, S16);
  k_mid<<<314, 256, 0, stream>>>(S16, WG16, wgb, PE16, S32, ENCSC, encidx, PSIC);
  k_pb<<<2048, 256, 0, stream>>>(PE16, PSIC, encidx, out);
}

// Round 6
// 751.690 us; speedup vs baseline: 1.6521x; 1.0327x over previous
//
#include <hip/hip_runtime.h>
#include <math.h>
#include <stdint.h>

// Problem constants
static const int VOC  = 32000;
static const int VT_  = 32100;

typedef __attribute__((ext_vector_type(8))) short bf16x8_t;
typedef __attribute__((ext_vector_type(4))) float f32x4_t;

__device__ __forceinline__ unsigned short f2bf(float f) {
  union { float f; unsigned int u; } v; v.f = f;
  unsigned int u = v.u;
  u = u + 0x7FFFu + ((u >> 16) & 1u);   // RNE
  return (unsigned short)(u >> 16);
}
__device__ __forceinline__ float bf2f(unsigned short u) {
  union { unsigned int i; float f; } w; w.i = ((unsigned int)u) << 16; return w.f;
}
__device__ __forceinline__ float bfbits(unsigned int u) {
  union { unsigned int i; float f; } w; w.i = u; return w.f;
}
// position of the j-th set bit (ascending) across the 128-bit mask (m0,m1)
__device__ __forceinline__ int nth_set(unsigned long long m0, unsigned long long m1, int j) {
  int c0 = __popcll(m0);
  unsigned long long m = m0; int base = 0;
  if (j >= c0) { j -= c0; m = m1; base = 64; }
  for (int k = 0; k < j; k++) m &= m - 1;
  return base + (__ffsll((long long)m) - 1);
}

// ------------------------------------------------ k_pre0: all dtype conversions
__global__ __launch_bounds__(256) void k_pre0(
    const float* __restrict__ wg, unsigned short* __restrict__ WG16,
    const float* __restrict__ whh, unsigned short* __restrict__ WHH16,
    const float* __restrict__ enc, unsigned short* __restrict__ EH,
    unsigned short* __restrict__ EL,
    const float* __restrict__ wo, unsigned short* __restrict__ WOH,
    unsigned short* __restrict__ WOL,
    const float* __restrict__ wih, unsigned short* __restrict__ WIH16,
    const float* __restrict__ embed, const int* __restrict__ inputs,
    unsigned short* __restrict__ X16) {
  int q = blockIdx.x, tid = threadIdx.x;
  if (q < 1024) {
    for (int i = q * 256 + tid; i < 2048000; i += 1024 * 256) {
      float4 f = ((const float4*)wg)[i];
      ushort4 o;
      o.x = f2bf(f.x); o.y = f2bf(f.y); o.z = f2bf(f.z); o.w = f2bf(f.w);
      ((ushort4*)WG16)[i] = o;
    }
  } else if (q < 1036) {
    for (int i = (q - 1024) * 256 + tid; i < 49152; i += 12 * 256) {
      float4 f = ((const float4*)whh)[i];
      ushort4 o;
      o.x = f2bf(f.x); o.y = f2bf(f.y); o.z = f2bf(f.z); o.w = f2bf(f.w);
      ((ushort4*)WHH16)[i] = o;
    }
  } else if (q < 1292) {
    for (int i = (q - 1036) * 256 + tid; i < 524288; i += 256 * 256) {
      float4 f = ((const float4*)enc)[i];
      ushort4 h, l;
      h.x = f2bf(f.x); l.x = f2bf(f.x - bf2f(h.x));
      h.y = f2bf(f.y); l.y = f2bf(f.y - bf2f(h.y));
      h.z = f2bf(f.z); l.z = f2bf(f.z - bf2f(h.z));
      h.w = f2bf(f.w); l.w = f2bf(f.w - bf2f(h.w));
      ((ushort4*)EH)[i] = h;
      ((ushort4*)EL)[i] = l;
    }
  } else if (q < 1300) {
    for (int i = (q - 1292) * 256 + tid; i < 32768; i += 8 * 256) {
      float4 f = ((const float4*)wo)[i];
      ushort4 h, l;
      h.x = f2bf(f.x); l.x = f2bf(f.x - bf2f(h.x));
      h.y = f2bf(f.y); l.y = f2bf(f.y - bf2f(h.y));
      h.z = f2bf(f.z); l.z = f2bf(f.z - bf2f(h.z));
      h.w = f2bf(f.w); l.w = f2bf(f.w - bf2f(h.w));
      ((ushort4*)WOH)[i] = h;
      ((ushort4*)WOL)[i] = l;
    }
  } else if (q < 1312) {
    for (int g = (q - 1300) * 256 + tid; g < 49152; g += 12 * 256) {
      int row = g >> 6, col = g & 63;
      float4 f = ((const float4*)(wih + (size_t)row * 768))[col];
      ushort4 o;
      o.x = f2bf(f.x); o.y = f2bf(f.y); o.z = f2bf(f.z); o.w = f2bf(f.w);
      ((ushort4*)WIH16)[g] = o;
    }
  } else {
    for (int g = (q - 1312) * 256 + tid; g < 131072; g += 128 * 256) {
      int r = g >> 6, col = g & 63;
      float4 f = ((const float4*)(embed + (size_t)inputs[r] * 256))[col];
      ushort4 o;
      o.x = f2bf(f.x); o.y = f2bf(f.y); o.z = f2bf(f.z); o.w = f2bf(f.w);
      ((ushort4*)X16)[g] = o;
    }
  }
}

// ------------------------------------------------ k_pre1: MFMA GEMMs + s0 + encih
__global__ __launch_bounds__(256) void k_pre1(
    const unsigned short* __restrict__ EH, const unsigned short* __restrict__ EL,
    const unsigned short* __restrict__ WOH, const unsigned short* __restrict__ WOL,
    const float* __restrict__ wob, float* __restrict__ ENCSC,
    const unsigned short* __restrict__ X16, const unsigned short* __restrict__ WIH16,
    const float* __restrict__ bih, float* __restrict__ XG,
    const float* __restrict__ enc, const float* __restrict__ bridge,
    float* __restrict__ S0,
    const float* __restrict__ wih, const int* __restrict__ encidx,
    const int* __restrict__ inputs, float* __restrict__ ENCIH) {
  __shared__ int flag;
  int q = blockIdx.x, tid = threadIdx.x;
  int wid = tid >> 6, lane = tid & 63;
  int wm = wid >> 1, wn = wid & 1;
  int quad = lane >> 4, l15 = lane & 15;
  if (q < 256) {
    // ---- enc split-MFMA: M=4096, N=256, K=512; 64x64 tile
    int bm = q >> 2, bn = q & 3;
    int r0 = bm * 64 + wm * 32, n0 = bn * 64 + wn * 32;
    f32x4_t acc[2][2];
#pragma unroll
    for (int i = 0; i < 2; i++)
#pragma unroll
      for (int j = 0; j < 2; j++) acc[i][j] = (f32x4_t){0.f, 0.f, 0.f, 0.f};
    for (int kc = 0; kc < 16; kc++) {
      int ko = kc * 32 + quad * 8;
      bf16x8_t ah[2], al[2], bh[2], bl[2];
#pragma unroll
      for (int i = 0; i < 2; i++) {
        size_t off = (size_t)(r0 + i * 16 + l15) * 512 + ko;
        ah[i] = *(const bf16x8_t*)(EH + off);
        al[i] = *(const bf16x8_t*)(EL + off);
      }
#pragma unroll
      for (int j = 0; j < 2; j++) {
        size_t off = (size_t)(n0 + j * 16 + l15) * 512 + ko;
        bh[j] = *(const bf16x8_t*)(WOH + off);
        bl[j] = *(const bf16x8_t*)(WOL + off);
      }
#pragma unroll
      for (int i = 0; i < 2; i++)
#pragma unroll
        for (int j = 0; j < 2; j++) {
          acc[i][j] = __builtin_amdgcn_mfma_f32_16x16x32_bf16(ah[i], bh[j], acc[i][j], 0, 0, 0);
          acc[i][j] = __builtin_amdgcn_mfma_f32_16x16x32_bf16(ah[i], bl[j], acc[i][j], 0, 0, 0);
          acc[i][j] = __builtin_amdgcn_mfma_f32_16x16x32_bf16(al[i], bh[j], acc[i][j], 0, 0, 0);
        }
    }
#pragma unroll
    for (int i = 0; i < 2; i++)
#pragma unroll
      for (int j = 0; j < 2; j++)
#pragma unroll
        for (int p = 0; p < 4; p++) {
          int row = r0 + i * 16 + quad * 4 + p;
          int col = n0 + j * 16 + l15;
          ENCSC[(size_t)row * 256 + col] = tanhf(acc[i][j][p] + wob[col]);
        }
  } else if (q < 640) {
    // ---- xg MFMA: M=2048, N=768, K=256; 64x64 tile
    int p2 = q - 256;
    int bm = p2 & 31, bn = p2 >> 5;
    int r0 = bm * 64 + wm * 32, n0 = bn * 64 + wn * 32;
    f32x4_t acc[2][2];
#pragma unroll
    for (int i = 0; i < 2; i++)
#pragma unroll
      for (int j = 0; j < 2; j++) acc[i][j] = (f32x4_t){0.f, 0.f, 0.f, 0.f};
    for (int kc = 0; kc < 8; kc++) {
      int ko = kc * 32 + quad * 8;
      bf16x8_t a[2], b[2];
#pragma unroll
      for (int i = 0; i < 2; i++)
        a[i] = *(const bf16x8_t*)(X16 + (size_t)(r0 + i * 16 + l15) * 256 + ko);
#pragma unroll
      for (int j = 0; j < 2; j++)
        b[j] = *(const bf16x8_t*)(WIH16 + (size_t)(n0 + j * 16 + l15) * 256 + ko);
#pragma unroll
      for (int i = 0; i < 2; i++)
#pragma unroll
        for (int j = 0; j < 2; j++)
          acc[i][j] = __builtin_amdgcn_mfma_f32_16x16x32_bf16(a[i], b[j], acc[i][j], 0, 0, 0);
    }
#pragma unroll
    for (int i = 0; i < 2; i++)
#pragma unroll
      for (int j = 0; j < 2; j++)
#pragma unroll
        for (int p = 0; p < 4; p++) {
          int row = r0 + i * 16 + quad * 4 + p;
          int col = n0 + j * 16 + l15;
          XG[(size_t)row * 768 + col] = acc[i][j][p] + bih[col];
        }
  } else if (q < 672) {
    // ---- s0
    int b = q - 640, h = tid;
    const float4* a4 = (const float4*)(enc + ((size_t)b * 128 + 127) * 512);
    const float4* w4 = (const float4*)(bridge + (size_t)h * 512);
    float acc = 0.f;
    for (int k = 0; k < 128; k++) {
      float4 a = a4[k], w = w4[k];
      acc += a.x * w.x + a.y * w.y + a.z * w.z + a.w * w.w;
    }
    S0[b * 256 + h] = acc;
  } else {
    // ---- encih (flag-gated)
    int bs = q - 672;
    int b = bs >> 7;
    int idx = encidx[bs];
    if (tid < 64) {
      unsigned long long m = __ballot(inputs[b * 64 + tid] == idx);
      if (tid == 0) flag = (m != 0ULL);
    }
    __syncthreads();
    if (!flag) return;
    const float4* e4 = (const float4*)(enc + (size_t)bs * 512);
    for (int d = tid; d < 768; d += 256) {
      const float4* w4 = (const float4*)(wih + (size_t)d * 768 + 256);
      float acc = 0.f;
      for (int k = 0; k < 128; k++) {
        float4 e = e4[k], w = w4[k];
        acc += e.x * w.x + e.y * w.y + e.z * w.z + e.w * w.w;
      }
      ENCIH[(size_t)bs * 768 + d] = acc;
    }
  }
}

// -------------------------------------------------------- sequential GRU (unchanged)
__global__ __launch_bounds__(768, 1) void k_seq(
    const unsigned short* __restrict__ whb,  // [768][256] bf16 W_hh
    const float* __restrict__ bhh,
    const float* __restrict__ xg, const float* __restrict__ encsc,
    const float* __restrict__ encih, const int* __restrict__ encidx,
    const int* __restrict__ inputs, const float* __restrict__ s0,
    float* __restrict__ S32, unsigned short* __restrict__ S16) {
  __shared__ float sbuf[256];
  __shared__ __align__(16) unsigned short sb16[256];
  __shared__ float ghp[768];
  __shared__ float psis[128];
  __shared__ int eidx_sh[128];
  __shared__ int inp_sh[64];
  __shared__ unsigned long long mmask[64][2];
  __shared__ __align__(16) unsigned short wlds[73728];  // 144 KB
  int b = blockIdx.x;
  int tid = threadIdx.x;
  int wid = tid >> 6, lane = tid & 63;
  int quad = lane >> 4, l15 = lane & 15;
  int n0 = wid * 64;
  int h = tid;
#pragma unroll
  for (int c = 0; c < 4; c++)
#pragma unroll
    for (int kt2 = 0; kt2 < 3; kt2++) {
      int4 v = *(const int4*)(whb + (size_t)(n0 + c * 16 + l15) * 256 + 160 + kt2 * 32 + quad * 8);
      *(int4*)(wlds + wid * 6144 + (c * 3 + kt2) * 512 + (l15 * 4 + quad) * 8) = v;
    }
  bf16x8_t wf[20];
#pragma unroll
  for (int c = 0; c < 4; c++)
#pragma unroll
    for (int kt = 0; kt < 5; kt++)
      wf[c * 5 + kt] = *(const bf16x8_t*)(whb + (size_t)(n0 + c * 16 + l15) * 256 + kt * 32 + quad * 8);
  float bR = 0.f, bZ = 0.f, bN = 0.f, ctxR = 0.f, ctxZ = 0.f, ctxN = 0.f;
  if (tid < 256) {
    bR = bhh[h]; bZ = bhh[256 + h]; bN = bhh[512 + h];
    float v = s0[b * 256 + tid];
    sbuf[tid] = v;
    sb16[tid] = f2bf(v);
  }
  if (tid < 128) eidx_sh[tid] = encidx[b * 128 + tid];
  if (tid < 64) inp_sh[tid] = inputs[b * 64 + tid];
  __syncthreads();
  if (tid < 128) {
    int e = eidx_sh[tid];
    for (int t = 0; t < 64; t++) {
      unsigned long long bal = __ballot(e == inp_sh[t]);
      if (lane == 0) mmask[t][wid] = bal;
    }
  }
  __syncthreads();
  for (int t = 0; t < 64; t++) {
    int r = b * 64 + t;
    float xr0 = 0.f, xr1 = 0.f, xr2 = 0.f;
    if (tid < 256) {
      const float* xr = xg + (size_t)r * 768;
      xr0 = xr[h]; xr1 = xr[256 + h]; xr2 = xr[512 + h];
    }
    f32x4_t a0 = {0.f,0.f,0.f,0.f}, a1 = {0.f,0.f,0.f,0.f};
    f32x4_t a2 = {0.f,0.f,0.f,0.f}, a3 = {0.f,0.f,0.f,0.f};
#pragma unroll
    for (int kt = 0; kt < 5; kt++) {
      bf16x8_t af = *(const bf16x8_t*)(sb16 + kt * 32 + quad * 8);
      a0 = __builtin_amdgcn_mfma_f32_16x16x32_bf16(af, wf[ 0 + kt], a0, 0, 0, 0);
      a1 = __builtin_amdgcn_mfma_f32_16x16x32_bf16(af, wf[ 5 + kt], a1, 0, 0, 0);
      a2 = __builtin_amdgcn_mfma_f32_16x16x32_bf16(af, wf[10 + kt], a2, 0, 0, 0);
      a3 = __builtin_amdgcn_mfma_f32_16x16x32_bf16(af, wf[15 + kt], a3, 0, 0, 0);
    }
#pragma unroll
    for (int kt2 = 0; kt2 < 3; kt2++) {
      bf16x8_t af = *(const bf16x8_t*)(sb16 + (5 + kt2) * 32 + quad * 8);
      const unsigned short* wb = wlds + wid * 6144 + kt2 * 512 + (l15 * 4 + quad) * 8;
      a0 = __builtin_amdgcn_mfma_f32_16x16x32_bf16(af, *(const bf16x8_t*)(wb +    0), a0, 0, 0, 0);
      a1 = __builtin_amdgcn_mfma_f32_16x16x32_bf16(af, *(const bf16x8_t*)(wb + 1536), a1, 0, 0, 0);
      a2 = __builtin_amdgcn_mfma_f32_16x16x32_bf16(af, *(const bf16x8_t*)(wb + 3072), a2, 0, 0, 0);
      a3 = __builtin_amdgcn_mfma_f32_16x16x32_bf16(af, *(const bf16x8_t*)(wb + 4608), a3, 0, 0, 0);
    }
    if (lane < 16) {
      ghp[n0 +      lane] = a0[0];
      ghp[n0 + 16 + lane] = a1[0];
      ghp[n0 + 32 + lane] = a2[0];
      ghp[n0 + 48 + lane] = a3[0];
    }
    __syncthreads();                                   // B1: gh complete
    if (tid < 256) {
      float hr = ghp[h] + bR;
      float hz = ghp[256 + h] + bZ;
      float hn = ghp[512 + h] + bN;
      float gr = xr0 + ctxR;
      float gz = xr1 + ctxZ;
      float gn = xr2 + ctxN;
      float rgate = 1.f / (1.f + expf(-(gr + hr)));
      float zgate = 1.f / (1.f + expf(-(gz + hz)));
      float ngate = tanhf(gn + rgate * hn);
      float sold = sbuf[h];
      float snew = (1.f - zgate) * ngate + zgate * sold;
      unsigned short u16 = f2bf(snew);
      S32[(size_t)r * 256 + h] = snew;
      S16[(size_t)r * 256 + h] = u16;
      sbuf[h] = snew;
      sb16[h] = u16;
    }
    __syncthreads();                                   // B2: s_t complete
    if (t == 63) break;
    unsigned long long m0 = mmask[t][0], m1 = mmask[t][1];
    int mc = __popcll(m0) + __popcll(m1);
    if (mc > 0) {                                      // uniform branch
      for (int j = wid; j < mc; j += 12) {
        int s = nth_set(m0, m1, j);
        const float4* e4 = (const float4*)(encsc + (size_t)(b * 128 + s) * 256);
        float4 ev = e4[lane];
        float4 sv = ((const float4*)sbuf)[lane];
        float v = ev.x * sv.x + ev.y * sv.y + ev.z * sv.z + ev.w * sv.w;
#pragma unroll
        for (int off = 32; off >= 1; off >>= 1) v += __shfl_down(v, off);
        if (lane == 0) psis[j] = v + (eidx_sh[s] == 0 ? -1000.f : 0.f);
      }
      __syncthreads();
      if (tid == 0) {
        float mx = -3e38f;
        for (int j = 0; j < mc; j++) mx = fmaxf(mx, psis[j]);
        if (mx < -500.f) {
          for (int j = 0; j < mc; j++) psis[j] = 0.f;
        } else {
          float ss = 0.f;
          for (int j = 0; j < mc; j++) { float e = expf(psis[j] - mx); psis[j] = e; ss += e; }
          float rs = 1.f / ss;
          for (int j = 0; j < mc; j++) psis[j] *= rs;
        }
      }
      __syncthreads();
      if (tid < 256) {
        ctxR = 0.f; ctxZ = 0.f; ctxN = 0.f;
        unsigned long long mm0 = m0, mm1 = m1;
        for (int j = 0; j < mc; j++) {
          int s;
          if (mm0) { s = __ffsll((long long)mm0) - 1; mm0 &= mm0 - 1; }
          else     { s = 64 + __ffsll((long long)mm1) - 1; mm1 &= mm1 - 1; }
          float c = psis[j];
          const float* e = encih + (size_t)(b * 128 + s) * 768;
          ctxR += c * e[h]; ctxZ += c * e[256 + h]; ctxN += c * e[512 + h];
        }
      }
    } else if (tid < 256) {
      ctxR = 0.f; ctxZ = 0.f; ctxN = 0.f;
    }
  }
}

// -------------------------------------------------- k_mid: psi_g GEMM (B-resident) + psi_c
// blocks [0,250): WG16 [128][256] resident in LDS, loop 16 mt tiles.
// Writes E = bf16(exp(psi)) AND per-(row, nc) partial sums of the ROUNDED E
// to PSUM[row][nc] (so k_pb's Z is self-consistent with the stored values).
// blocks [250,314): psic = S32 x ENCSC^T + pad mask (fp32 precision kept).
__global__ __launch_bounds__(256) void k_mid(const unsigned short* __restrict__ S16,
                                             const unsigned short* __restrict__ WG16,
                                             const float* __restrict__ wgb,
                                             unsigned short* __restrict__ pe16,
                                             float* __restrict__ psum,
                                             const float* __restrict__ S32,
                                             const float* __restrict__ encsc,
                                             const int* __restrict__ encidx,
                                             float* __restrict__ psic) {
  int q = blockIdx.x;
  int tid = threadIdx.x;
  if (q >= 250) {
    // ---- psic branch
    int q2 = q - 250;
    int b = q2 >> 1, ny = q2 & 1;
    int ti = tid & 15, tj = tid >> 4;
    int r0 = b * 64 + ti * 4;
    int s0 = ny * 64 + tj * 4;
    const float4* A[4]; const float4* B[4];
#pragma unroll
    for (int i = 0; i < 4; i++) A[i] = (const float4*)(S32 + (size_t)(r0 + i) * 256);
#pragma unroll
    for (int j = 0; j < 4; j++) B[j] = (const float4*)(encsc + (size_t)(b * 128 + s0 + j) * 256);
    float acc[4][4];
#pragma unroll
    for (int i = 0; i < 4; i++)
#pragma unroll
      for (int j = 0; j < 4; j++) acc[i][j] = 0.f;
    for (int k = 0; k < 64; k++) {
      float4 a[4], bb[4];
#pragma unroll
      for (int i = 0; i < 4; i++) a[i] = A[i][k];
#pragma unroll
      for (int j = 0; j < 4; j++) bb[j] = B[j][k];
#pragma unroll
      for (int i = 0; i < 4; i++)
#pragma unroll
        for (int j = 0; j < 4; j++)
          acc[i][j] += a[i].x * bb[j].x + a[i].y * bb[j].y + a[i].z * bb[j].z + a[i].w * bb[j].w;
    }
#pragma unroll
    for (int i = 0; i < 4; i++)
#pragma unroll
      for (int j = 0; j < 4; j++) {
        float v = acc[i][j] + (encidx[b * 128 + s0 + j] == 0 ? -1000.f : 0.f);
        psic[(size_t)(r0 + i) * 128 + s0 + j] = v;
      }
    return;
  }
  // ---- psi_g branch: B-resident over mt loop
  __shared__ unsigned short lB[128 * 256];   // 64 KB
  __shared__ unsigned short lA[128 * 256];   // 64 KB
  __shared__ float zpart[2][128];            // 1 KB per-half row sums
  int nc = q;
  int wid = tid >> 6, lane = tid & 63;
  int wm = wid >> 1, wn = wid & 1;
  int quad = lane >> 4, l15 = lane & 15;
  // stage B once (swizzled source chunks)
#pragma unroll
  for (int u = 0; u < 16; u++) {
    int c = u * 256 + tid;
    int row = c >> 5, ch = c & 31;
    int sch = (ch & 24) | ((ch & 7) ^ (row & 7));
    __builtin_amdgcn_global_load_lds(
        (const __attribute__((address_space(1))) unsigned int*)(WG16 + (size_t)(nc * 128 + row) * 256 + sch * 8),
        (__attribute__((address_space(3))) unsigned int*)(lB + c * 8), 16, 0, 0);
  }
  float bj[4];
#pragma unroll
  for (int j = 0; j < 4; j++) bj[j] = wgb[nc * 128 + wn * 64 + j * 16 + l15];
  for (int mt = 0; mt < 16; mt++) {
    // stage A tile for this mt
#pragma unroll
    for (int u = 0; u < 16; u++) {
      int c = u * 256 + tid;
      int row = c >> 5, ch = c & 31;
      int sch = (ch & 24) | ((ch & 7) ^ (row & 7));
      __builtin_amdgcn_global_load_lds(
          (const __attribute__((address_space(1))) unsigned int*)(S16 + (size_t)(mt * 128 + row) * 256 + sch * 8),
          (__attribute__((address_space(3))) unsigned int*)(lA + c * 8), 16, 0, 0);
    }
    __syncthreads();   // A (and on mt=0, B) staged
    f32x4_t acc[4][4];
#pragma unroll
    for (int i = 0; i < 4; i++)
#pragma unroll
      for (int j = 0; j < 4; j++) acc[i][j] = (f32x4_t){0.f, 0.f, 0.f, 0.f};
#pragma unroll
    for (int kc = 0; kc < 8; kc++) {
      int g = kc * 4 + quad;
      int slotoff = ((g & 24) | ((g & 7) ^ (l15 & 7))) * 8;
      bf16x8_t af[4], bfr[4];
#pragma unroll
      for (int i = 0; i < 4; i++)
        af[i] = *(const bf16x8_t*)(lA + (wm * 64 + i * 16 + l15) * 256 + slotoff);
#pragma unroll
      for (int j = 0; j < 4; j++)
        bfr[j] = *(const bf16x8_t*)(lB + (wn * 64 + j * 16 + l15) * 256 + slotoff);
#pragma unroll
      for (int i = 0; i < 4; i++)
#pragma unroll
        for (int j = 0; j < 4; j++)
          acc[i][j] = __builtin_amdgcn_mfma_f32_16x16x32_bf16(af[i], bfr[j], acc[i][j], 0, 0, 0);
    }
    // epilogue for this mt: store rounded E + reduce rounded row sums
#pragma unroll
    for (int i = 0; i < 4; i++)
#pragma unroll
      for (int p = 0; p < 4; p++) {
        int rl = wm * 64 + i * 16 + quad * 4 + p;   // row within tile
        int rg = mt * 128 + rl;
        size_t base = (size_t)rg * 32000 + nc * 128 + wn * 64 + l15;
        float rs = 0.f;
#pragma unroll
        for (int j = 0; j < 4; j++) {
          unsigned short us = f2bf(expf(acc[i][j][p] + bj[j]));
          pe16[base + j * 16] = us;
          rs += bf2f(us);
        }
#pragma unroll
        for (int off = 1; off < 16; off <<= 1) rs += __shfl_xor(rs, off);
        if (l15 == 0) zpart[wn][rl] = rs;
      }
    __syncthreads();   // zpart complete; also protects lA reuse
    if (tid < 128)
      psum[(size_t)(mt * 128 + tid) * 256 + nc] = zpart[0][tid] + zpart[1][tid];
  }
}

// pass B: Z from PSUM partials + psi_c; then pure copy-transform stream.
// One block per output row; loads and stores interleaved in flight.
__global__ __launch_bounds__(256) void k_pb(const unsigned short* __restrict__ pe16,
                                            const float* __restrict__ psum,
                                            const float* __restrict__ psic,
                                            const int* __restrict__ encidx,
                                            float* __restrict__ outp) {
  __shared__ float red[8];
  int r = blockIdx.x;          // 0..2047
  int b = r >> 6;
  int tid = threadIdx.x;
  int wid = tid >> 6, lane = tid & 63;
  const unsigned short* prow = pe16 + (size_t)r * 32000;
  float* orow = outp + (size_t)r * VT_;
  // sum of rounded E over 250 chunk partials
  float zp = (tid < 250) ? psum[(size_t)r * 256 + tid] : 0.f;
#pragma unroll
  for (int off = 32; off >= 1; off >>= 1) zp += __shfl_xor(zp, off);
  if (lane == 0) red[wid] = zp;
  // psi_c max
  float pc = (tid < 128) ? psic[(size_t)r * 128 + tid] : -3e38f;
  float mv = pc;
#pragma unroll
  for (int off = 32; off >= 1; off >>= 1) mv = fmaxf(mv, __shfl_xor(mv, off));
  if (lane == 0) red[4 + wid] = mv;
  __syncthreads();
  float sumEt = red[0] + red[1] + red[2] + red[3];
  float Mc = fmaxf(fmaxf(red[4], red[5]), fmaxf(red[6], red[7]));
  float D = fmaxf(Mc - 30.f, 0.f);
  float w = expf(-D);
  __syncthreads();
  float ec = (tid < 128) ? expf(pc - D) : 0.f;
  float zt = ec;
#pragma unroll
  for (int off = 32; off >= 1; off >>= 1) zt += __shfl_xor(zt, off);
  if (lane == 0) red[wid] = zt;
  __syncthreads();
  float Z = w * sumEt + (red[0] + red[1] + red[2] + red[3]);
  float gs = w / Z;
  // stream: read 8 bf16, write 8 fp32 per thread-iteration
  for (int u = 0; u < 16; u++) {
    int c8 = u * 256 + tid;
    if (c8 < 4000) {
      int c0 = c8 * 8;
      int4 v = *(const int4*)(prow + c0);
      unsigned int xs0 = (unsigned int)v.x, xs1 = (unsigned int)v.y;
      unsigned int xs2 = (unsigned int)v.z, xs3 = (unsigned int)v.w;
      float4 o0, o1;
      o0.x = bfbits(xs0 << 16) * gs;         o0.y = bfbits(xs0 & 0xffff0000u) * gs;
      o0.z = bfbits(xs1 << 16) * gs;         o0.w = bfbits(xs1 & 0xffff0000u) * gs;
      o1.x = bfbits(xs2 << 16) * gs;         o1.y = bfbits(xs2 & 0xffff0000u) * gs;
      o1.z = bfbits(xs3 << 16) * gs;         o1.w = bfbits(xs3 & 0xffff0000u) * gs;
      *(float4*)(orow + c0) = o0;
      *(float4*)(orow + c0 + 4) = o1;
    }
  }
  if (tid < 100) orow[32000 + tid] = 1e-4f;
  __syncthreads();   // drains vmem: streamed stores visible in L2 before RMW
  if (tid < 128) {
    int idx = encidx[b * 128 + tid];
    atomicAdd(&orow[idx], ec / Z);
  }
}

// ---------------------------------------------------------------- launch
extern "C" void kernel_launch(void* const* d_in, const int* in_sizes, int n_in,
                              void* d_out, int out_size, void* d_ws, size_t ws_size,
                              hipStream_t stream) {
  (void)in_sizes; (void)n_in; (void)out_size; (void)ws_size;
  const int*   inputs  = (const int*)d_in[0];
  const float* encoded = (const float*)d_in[1];
  const int*   encidx  = (const int*)d_in[2];
  const float* bridge  = (const float*)d_in[3];
  const float* embed   = (const float*)d_in[4];
  const float* wih     = (const float*)d_in[5];
  const float* whh     = (const float*)d_in[6];
  const float* bih     = (const float*)d_in[7];
  const float* bhh     = (const float*)d_in[8];
  const float* wg      = (const float*)d_in[9];
  const float* wgb     = (const float*)d_in[10];
  const float* wo      = (const float*)d_in[11];
  const float* wob     = (const float*)d_in[12];
  float* out = (float*)d_out;

  char* ws = (char*)d_ws;
  size_t off = 0;
  auto alloc = [&](size_t bytes) -> void* {
    void* p = ws + off;
    off += (bytes + 255) & ~(size_t)255;
    return p;
  };
  unsigned short* WG16  = (unsigned short*)alloc((size_t)32000 * 256 * 2);
  unsigned short* WHH16 = (unsigned short*)alloc((size_t)768 * 256 * 2);
  unsigned short* EH    = (unsigned short*)alloc((size_t)4096 * 512 * 2);
  unsigned short* EL    = (unsigned short*)alloc((size_t)4096 * 512 * 2);
  unsigned short* WOH   = (unsigned short*)alloc((size_t)256 * 512 * 2);
  unsigned short* WOL   = (unsigned short*)alloc((size_t)256 * 512 * 2);
  unsigned short* WIH16 = (unsigned short*)alloc((size_t)768 * 256 * 2);
  unsigned short* X16   = (unsigned short*)alloc((size_t)2048 * 256 * 2);
  float* S32            = (float*)alloc((size_t)2048 * 256 * 4);
  unsigned short* S16   = (unsigned short*)alloc((size_t)2048 * 256 * 2);
  float* ENCSC          = (float*)alloc((size_t)4096 * 256 * 4);
  float* ENCIH          = (float*)alloc((size_t)4096 * 768 * 4);
  float* XG             = (float*)alloc((size_t)2048 * 768 * 4);
  float* S0             = (float*)alloc((size_t)32 * 256 * 4);
  float* PSIC           = (float*)alloc((size_t)2048 * 128 * 4);
  float* PSUM           = (float*)alloc((size_t)2048 * 256 * 4);
  unsigned short* PE16  = (unsigned short*)alloc((size_t)2048 * 32000 * 2);

  k_pre0<<<1440, 256, 0, stream>>>(wg, WG16, whh, WHH16, encoded, EH, EL,
                                   wo, WOH, WOL, wih, WIH16, embed, inputs, X16);
  k_pre1<<<4768, 256, 0, stream>>>(EH, EL, WOH, WOL, wob, ENCSC,
                                   X16, WIH16, bih, XG,
                                   encoded, bridge, S0, wih, encidx, inputs, ENCIH);
  k_seq<<<32, 768, 0, stream>>>(WHH16, bhh, XG, ENCSC, ENCIH, encidx, inputs, S0, S32, S16);
  k_mid<<<314, 256, 0, stream>>>(S16, WG16, wgb, PE16, PSUM, S32, ENCSC, encidx, PSIC);
  k_pb<<<2048, 256, 0, stream>>>(PE16, PSUM, PSIC, encidx, out);
}